// Round 5
// baseline (1377.834 us; speedup 1.0000x reference)
//
#include <hip/hip_runtime.h>
#include <math.h>

// Problem constants
#define NBATCH 16
#define CDIM   384
#define NPIX   4096      // H*W = 64*64
#define HDCH   96        // channels per head
#define NROWS  65536     // NBATCH*NPIX
#define KVHALF 25165824  // 65536*384 = elems in KT (== elems in V)

typedef unsigned short bf16;
typedef __attribute__((ext_vector_type(8))) short short8;
typedef __attribute__((ext_vector_type(4))) float floatx4;

union S8U { short8 v; bf16 u[8]; };

__device__ __forceinline__ float b2f(bf16 u) {
    union { unsigned int i; float f; } c; c.i = ((unsigned int)u) << 16; return c.f;
}
__device__ __forceinline__ bf16 f2b(float f) {
    union { float f; unsigned int i; } c; c.f = f;
    unsigned int r = (c.i + 0x7FFFu + ((c.i >> 16) & 1u)) >> 16;
    return (bf16)r;
}

// async global->LDS, 16B per lane. LDS dest is wave-uniform base + lane*16.
__device__ __forceinline__ void gload16(const bf16* g, bf16* l) {
    __builtin_amdgcn_global_load_lds(
        (const __attribute__((address_space(1))) unsigned int*)g,
        (__attribute__((address_space(3))) unsigned int*)l, 16, 0, 0);
}

// ---------------------------------------------------------------------------
// 0) zero scratch accumulators
// ---------------------------------------------------------------------------
__global__ __launch_bounds__(256) void zero_kernel(float* __restrict__ p) {
    p[blockIdx.x * 256 + threadIdx.x] = 0.0f;
}

// 0b) convert fp32 weights -> bf16 (float4/ushort4 vectorized)
__global__ __launch_bounds__(256) void wcvt_kernel(const float* __restrict__ w,
                                                   bf16* __restrict__ o, int n4) {
    int i = blockIdx.x * 256 + threadIdx.x;
    if (i < n4) {
        float4 v = ((const float4*)w)[i];
        ushort4 u;
        u.x = f2b(v.x); u.y = f2b(v.y); u.z = f2b(v.z); u.w = f2b(v.w);
        ((ushort4*)o)[i] = u;
    }
}

// ---------------------------------------------------------------------------
// 1) Fourier positional embedding: pos[n, c] (bf16 out)
// ---------------------------------------------------------------------------
__global__ __launch_bounds__(128) void pos_kernel(const float* __restrict__ pos_w,
                                                  const float* __restrict__ pos_b,
                                                  bf16* __restrict__ pos) {
    __shared__ float feat[64];
    int n = blockIdx.x;
    int yi = n >> 6, xi = n & 63;
    int tid = threadIdx.x;
    if (tid < 64) {
        int j = tid & 31;
        int isx = tid >= 32;
        float base = (float)((isx ? xi : yi) + 1);
        float val = base / (64.0f + 1e-6f) * 6.283185307179586f;
        float e = (float)(2 * (j >> 1)) / 32.0f;
        float dt = powf(10000.0f, e);
        float a = val / dt;
        feat[isx * 32 + j] = (j & 1) ? cosf(a) : sinf(a);
    }
    __syncthreads();
    for (int c = tid; c < CDIM; c += 128) {
        float s = pos_b[c];
        const float* wr = pos_w + c * 64;
        #pragma unroll 16
        for (int j = 0; j < 64; ++j) s += feat[j] * wr[j];
        pos[n * CDIM + c] = f2b(s);
    }
}

// ---------------------------------------------------------------------------
// 2) Depthwise 3x3 conv (pad 1). xin fp32 chunk (+ prev bf16 chunk), out bf16.
// ---------------------------------------------------------------------------
__global__ __launch_bounds__(256) void dwconv_kernel(const float* __restrict__ xin, int in_ch0,
                                                     const bf16* __restrict__ prev, int prev_ch0,
                                                     const float* __restrict__ w,
                                                     const float* __restrict__ bias,
                                                     bf16* __restrict__ out, int out_ch0) {
    __shared__ float tile[66][66];
    int b = blockIdx.x / 96, c = blockIdx.x % 96;
    const float* ip = xin + (b * CDIM + in_ch0 + c) * NPIX;
    const bf16* pp = prev ? prev + (b * CDIM + prev_ch0 + c) * NPIX : nullptr;
    int tid = threadIdx.x;
    for (int i = tid; i < 66 * 66; i += 256) {
        int yy = i / 66 - 1, xx = i % 66 - 1;
        float v = 0.0f;
        if (yy >= 0 && yy < 64 && xx >= 0 && xx < 64) {
            v = ip[yy * 64 + xx];
            if (pp) v += b2f(pp[yy * 64 + xx]);
        }
        tile[i / 66][i % 66] = v;
    }
    __syncthreads();
    float wc[9];
    #pragma unroll
    for (int j = 0; j < 9; ++j) wc[j] = w[c * 9 + j];
    float b0 = bias[c];
    bf16* op = out + (b * CDIM + out_ch0 + c) * NPIX;
    for (int p = tid; p < NPIX; p += 256) {
        int y = p >> 6, x = p & 63;
        float a = b0;
        #pragma unroll
        for (int dy = 0; dy < 3; ++dy)
            #pragma unroll
            for (int dx = 0; dx < 3; ++dx)
                a += tile[y + dy][x + dx] * wc[dy * 3 + dx];
        op[p] = f2b(a);
    }
}

// convert channels [288:384) of x (fp32) into xcat (bf16)
__global__ __launch_bounds__(256) void convert_last_kernel(const float* __restrict__ x,
                                                           bf16* __restrict__ xcat) {
    int idx = blockIdx.x * 256 + threadIdx.x;   // 16*96*4096/4 = 1,572,864 threads
    int b = idx / (96 * 1024);
    int rem = idx % (96 * 1024);
    const float4* src = (const float4*)(x + (b * CDIM + 288) * NPIX);
    float4 v = src[rem];
    ushort4 o;
    o.x = f2b(v.x); o.y = f2b(v.y); o.z = f2b(v.z); o.w = f2b(v.w);
    ((ushort4*)(xcat + (b * CDIM + 288) * NPIX))[rem] = o;
}

// ---------------------------------------------------------------------------
// 3) x3[b,n,c] = xcat[b,c,n] + pos[n,c]   (LDS 32x32 transpose, bf16 io)
// ---------------------------------------------------------------------------
__global__ void x3_kernel(const bf16* __restrict__ xcat, const bf16* __restrict__ pos,
                          bf16* __restrict__ x3) {
    __shared__ float t[32][33];
    int c0 = blockIdx.x * 32, n0 = blockIdx.y * 32, b = blockIdx.z;
    int tx = threadIdx.x, ty = threadIdx.y;
    #pragma unroll
    for (int k = 0; k < 4; ++k) {
        int cl = ty + k * 8;
        t[cl][tx] = b2f(xcat[(b * CDIM + c0 + cl) * NPIX + n0 + tx]);
    }
    __syncthreads();
    #pragma unroll
    for (int k = 0; k < 4; ++k) {
        int nl = ty + k * 8;
        x3[(b * NPIX + n0 + nl) * CDIM + c0 + tx] =
            f2b(t[tx][nl] + b2f(pos[(n0 + nl) * CDIM + c0 + tx]));
    }
}

// ---------------------------------------------------------------------------
// 4) Row LayerNorm over C=384, bf16 io. map=1: fold-remap source row.
// ---------------------------------------------------------------------------
__global__ __launch_bounds__(128) void ln_kernel(const bf16* __restrict__ in,
                                                 const float* __restrict__ w,
                                                 const float* __restrict__ b,
                                                 bf16* __restrict__ out, int map) {
    int r = blockIdx.x;
    int src = r;
    if (map == 1) {
        int bb = r >> 12;
        int p = r & 4095;
        int y = p >> 6, x = p & 63;
        int patch = ((y & 1) << 1) | (x & 1);
        int blk = ((y >> 1) << 5) | (x >> 1);
        src = ((bb << 2) + patch) * 1024 + blk;
    }
    const bf16* row = in + src * CDIM;
    int tid = threadIdx.x;
    float v[3];
    float s1 = 0.0f, s2 = 0.0f;
    #pragma unroll
    for (int i = 0; i < 3; ++i) {
        v[i] = b2f(row[tid + i * 128]);
        s1 += v[i];
        s2 += v[i] * v[i];
    }
    __shared__ float r1[128], r2[128];
    r1[tid] = s1; r2[tid] = s2;
    __syncthreads();
    for (int off = 64; off > 0; off >>= 1) {
        if (tid < off) { r1[tid] += r1[tid + off]; r2[tid] += r2[tid + off]; }
        __syncthreads();
    }
    float mean = r1[0] * (1.0f / 384.0f);
    float var = fmaxf(r2[0] * (1.0f / 384.0f) - mean * mean, 0.0f);
    float rstd = rsqrtf(var + 1e-6f);
    #pragma unroll
    for (int i = 0; i < 3; ++i) {
        int c = tid + i * 128;
        out[r * CDIM + c] = f2b((v[i] - mean) * rstd * w[c] + b[c]);
    }
}

// ---------------------------------------------------------------------------
// 5) MFMA GEMM: C[M,Nout] = epi(A[M,K](bf16) @ W[Nout,K]^T(bf16) + bias)
//    128x128 tile, BK=32, 4 waves, 16x16x32 bf16 MFMA.
//    4-buffer depth-3-ahead software pipeline (T3+T4, counted vmcnt):
//      iter t: STAGE(buf[(t+3)&3]) ; compute buf[t&3] ; vmcnt(8) ; s_barrier
//    (3 stages in flight; never drains to 0 in the main loop.)
//    XCD-chunked swizzle (T1): flat dispatch d -> wg=(d%8)*(nwg/8)+d/8, then
//    x-major/y-inner decompose so each A panel is read ny times consecutively
//    on ONE XCD (L2-hot) and fetched from HBM exactly once.
//    Staging: global_load_lds width-16, linear LDS [128][32] with both-sides
//    involution swizzle: phys chunk = logical chunk XOR ((row>>1)&3).
//    mode 0: plain   mode 1: exact GELU   mode 2: res(bf16) + scalevec[c]*(.)
//    mode 3: kv-split — cols<384 write transposed KT[(row>>nlog2)*384+col][row&mask],
//            cols>=384 write V at C+KVHALF, [row][col-384]
// ---------------------------------------------------------------------------
__global__ __launch_bounds__(256) void mfma_gemm_kernel(const bf16* __restrict__ A,
                                                        const bf16* __restrict__ W,
                                                        const float* __restrict__ bias,
                                                        bf16* __restrict__ C,
                                                        int M, int Nout, int K, int mode,
                                                        const bf16* __restrict__ res,
                                                        const float* __restrict__ scalevec,
                                                        int nlog2) {
    __shared__ bf16 As[4][128][32];   // 32 KB
    __shared__ bf16 Bs[4][128][32];   // 32 KB
    // --- XCD-chunked swizzle + panel-major decomposition ---
    int nx = gridDim.x, ny = gridDim.y;
    int d = blockIdx.x + nx * blockIdx.y;     // flat dispatch id (x fastest)
    int nwg = nx * ny;
    int xt, yt;
    if ((nwg & 7) == 0) {
        int cpx = nwg >> 3;
        int wg = (d & 7) * cpx + (d >> 3);    // contiguous range per XCD
        xt = wg / ny;                         // A-panel index (owned by one XCD)
        yt = wg % ny;
    } else {
        xt = blockIdx.x; yt = blockIdx.y;
    }
    int m0 = xt * 128;
    int n0 = yt * 128;
    int tid = threadIdx.x;
    int wave = tid >> 6, lane = tid & 63;
    int wm = (wave & 1) * 64;
    int wn = (wave >> 1) * 64;
    int quad = lane >> 4;
    int lrow = lane & 15;

    // --- staging address decomposition (per-thread, loop-invariant) ---
    // physical byte within 8KB tile: p = call*4096 + wave*1024 + lane*16
    // logical byte o = p ^ (((p>>7)&3)<<4); row = o>>6, chunk=(o>>4)&3
    int p0b = wave * 1024 + lane * 16;
    int o0 = p0b ^ (((p0b >> 7) & 3) << 4);
    int r0 = o0 >> 6;
    int ch0 = (o0 >> 4) & 3;

    const bf16* aSrc0 = A + (size_t)(m0 + r0) * K + ch0 * 8;
    const bf16* aSrc1 = A + (size_t)(m0 + r0 + 64) * K + ch0 * 8;
    const bf16* bSrc0 = W + (size_t)(n0 + r0) * K + ch0 * 8;
    const bf16* bSrc1 = W + (size_t)(n0 + r0 + 64) * K + ch0 * 8;
    bf16* lA0 = &As[0][0][0] + wave * 512;          // wave-uniform LDS bases (buffer 0)
    bf16* lA1 = &As[0][0][0] + 2048 + wave * 512;
    bf16* lB0 = &Bs[0][0][0] + wave * 512;
    bf16* lB1 = &Bs[0][0][0] + 2048 + wave * 512;

    // swizzled read column (elems)
    int rcol = (quad ^ ((lrow >> 1) & 3)) * 8;
    int NT = K >> 5;

#define STAGE(bi_, t_) do { int _off = (bi_) * 4096; int _kk = (t_) * 32; \
        gload16(aSrc0 + _kk, lA0 + _off); \
        gload16(aSrc1 + _kk, lA1 + _off); \
        gload16(bSrc0 + _kk, lB0 + _off); \
        gload16(bSrc1 + _kk, lB1 + _off); } while (0)

    floatx4 acc[4][4] = {};

    // prologue: three tiles in flight, wait for tile 0 only
    STAGE(0, 0);
    STAGE(1, 1);
    STAGE(2, 2);
    asm volatile("s_waitcnt vmcnt(8)" ::: "memory");
    __builtin_amdgcn_s_barrier();
    __builtin_amdgcn_sched_barrier(0);

    for (int t = 0; t < NT; ++t) {
        int bi = t & 3;
        if (t + 3 < NT) STAGE((t + 3) & 3, t + 3);   // overwrites buf (t-1)&3: readers passed barrier(t-1)
        short8 af[4], bfr[4];
        #pragma unroll
        for (int i = 0; i < 4; ++i)
            af[i] = *(const short8*)(&As[bi][wm + i * 16 + lrow][rcol]);
        #pragma unroll
        for (int j = 0; j < 4; ++j)
            bfr[j] = *(const short8*)(&Bs[bi][wn + j * 16 + lrow][rcol]);
        #pragma unroll
        for (int i = 0; i < 4; ++i)
            #pragma unroll
            for (int j = 0; j < 4; ++j)
                acc[i][j] = __builtin_amdgcn_mfma_f32_16x16x32_bf16(af[i], bfr[j], acc[i][j], 0, 0, 0);
        if (t + 1 < NT) {
            if (t + 3 < NT)      asm volatile("s_waitcnt vmcnt(8)" ::: "memory"); // t+1 landed; t+2,t+3 in flight
            else if (t + 2 < NT) asm volatile("s_waitcnt vmcnt(4)" ::: "memory"); // t+1 landed; t+2 in flight
            else                 asm volatile("s_waitcnt vmcnt(0)" ::: "memory"); // last prefetch landed
            __builtin_amdgcn_s_barrier();
            __builtin_amdgcn_sched_barrier(0);
        }
    }
#undef STAGE

    if (mode == 3) {
        int nmask = (1 << nlog2) - 1;
        #pragma unroll
        for (int i = 0; i < 4; ++i) {
            int rowb = m0 + wm + i * 16 + quad * 4;
            int bb = rowb >> nlog2, tok = rowb & nmask;
            #pragma unroll
            for (int j = 0; j < 4; ++j) {
                int col = n0 + wn + j * 16 + lrow;
                float bv = bias[col];
                if (col < 384) {
                    ushort4 o;
                    o.x = f2b(acc[i][j][0] + bv);
                    o.y = f2b(acc[i][j][1] + bv);
                    o.z = f2b(acc[i][j][2] + bv);
                    o.w = f2b(acc[i][j][3] + bv);
                    *(ushort4*)(C + ((((size_t)bb * 384 + col) << nlog2) | (size_t)tok)) = o;
                } else {
                    bf16* vp = C + KVHALF + (size_t)rowb * 384 + (col - 384);
                    #pragma unroll
                    for (int r = 0; r < 4; ++r)
                        vp[(size_t)r * 384] = f2b(acc[i][j][r] + bv);
                }
            }
        }
        return;
    }

    // epilogue: D row = quad*4+reg (within 16-tile), col = lrow
    #pragma unroll
    for (int i = 0; i < 4; ++i) {
        int rowb = m0 + wm + i * 16 + quad * 4;
        #pragma unroll
        for (int j = 0; j < 4; ++j) {
            int col = n0 + wn + j * 16 + lrow;
            float bv = bias[col];
            #pragma unroll
            for (int r = 0; r < 4; ++r) {
                int row = rowb + r;
                float v = acc[i][j][r] + bv;
                if (mode == 1) {
                    v = 0.5f * v * (1.0f + erff(v * 0.70710678118654752f));
                } else if (mode == 2) {
                    v = b2f(res[(size_t)row * Nout + col]) + scalevec[col] * v;
                }
                C[(size_t)row * Nout + col] = f2b(v);
            }
        }
    }
}

// ---------------------------------------------------------------------------
// 6) K row sum-of-squares over tokens, reading KT[b*384+c][n]. One block/row.
// ---------------------------------------------------------------------------
__global__ __launch_bounds__(256) void knormsq2_kernel(const bf16* __restrict__ KT,
                                                       float* __restrict__ outk, int n_len) {
    int row = blockIdx.x;
    const bf16* p = KT + (size_t)row * n_len;
    int tid = threadIdx.x;
    float s = 0.0f;
    for (int i = tid * 8; i < n_len; i += 256 * 8) {
        S8U t; t.v = *(const short8*)(p + i);
        #pragma unroll
        for (int j = 0; j < 8; ++j) { float f = b2f(t.u[j]); s += f * f; }
    }
    __shared__ float red[256];
    red[tid] = s;
    __syncthreads();
    for (int off = 128; off > 0; off >>= 1) {
        if (tid < off) red[tid] += red[tid + off];
        __syncthreads();
    }
    if (tid == 0) outk[row] = red[0];
}

// ---------------------------------------------------------------------------
// 7a) S accumulate via MFMA: S[pair,c,d] += sum_{n in chunk} Q[c,n]*K[d,n]
// ---------------------------------------------------------------------------
__global__ __launch_bounds__(256) void chan_qk_mfma(const float* __restrict__ qf,
                                                    const bf16* __restrict__ qb,
                                                    const bf16* __restrict__ KT,
                                                    float* __restrict__ Sg,
                                                    int n_len, int nchunks, int mode) {
    int pair = blockIdx.x / nchunks, ck = blockIdx.x % nchunks;
    int bi = pair >> 2, h = pair & 3;
    int koff = h * HDCH;
    int chunk = n_len / nchunks;
    int nbeg = ck * chunk;
    int tid = threadIdx.x;
    int wave = tid >> 6, lane = tid & 63;
    int lr = lane & 15, q = lane >> 4;
    int c0 = (wave & 1) * 48;
    int d0 = (wave >> 1) * 48;
    floatx4 acc[3][3] = {};
    const size_t qbase = (size_t)(bi * CDIM + koff) * n_len;
    const bf16* kbase = KT + (size_t)(bi * CDIM + koff) * n_len;
    for (int nn = 0; nn < chunk; nn += 32) {
        int n0 = nbeg + nn + q * 8;
        short8 af[3], bfr[3];
        if (mode == 0) {
            #pragma unroll
            for (int i = 0; i < 3; ++i) {
                const float* qp = qf + qbase + (size_t)(c0 + i * 16 + lr) * n_len + n0;
                float4 f0 = *(const float4*)qp;
                float4 f1 = *(const float4*)(qp + 4);
                S8U t;
                t.u[0] = f2b(f0.x); t.u[1] = f2b(f0.y); t.u[2] = f2b(f0.z); t.u[3] = f2b(f0.w);
                t.u[4] = f2b(f1.x); t.u[5] = f2b(f1.y); t.u[6] = f2b(f1.z); t.u[7] = f2b(f1.w);
                af[i] = t.v;
            }
        } else {
            #pragma unroll
            for (int i = 0; i < 3; ++i)
                af[i] = *(const short8*)(qb + qbase + (size_t)(c0 + i * 16 + lr) * n_len + n0);
        }
        #pragma unroll
        for (int j = 0; j < 3; ++j)
            bfr[j] = *(const short8*)(kbase + (size_t)(d0 + j * 16 + lr) * n_len + n0);
        #pragma unroll
        for (int i = 0; i < 3; ++i)
            #pragma unroll
            for (int j = 0; j < 3; ++j)
                acc[i][j] = __builtin_amdgcn_mfma_f32_16x16x32_bf16(af[i], bfr[j], acc[i][j], 0, 0, 0);
    }
    float* Sp = Sg + (size_t)pair * 9216;
    #pragma unroll
    for (int i = 0; i < 3; ++i) {
        int rowb = c0 + i * 16 + q * 4;
        #pragma unroll
        for (int j = 0; j < 3; ++j) {
            int col = d0 + j * 16 + lr;
            #pragma unroll
            for (int r = 0; r < 4; ++r)
                atomicAdd(&Sp[(rowb + r) * 96 + col], acc[i][j][r]);
        }
    }
}

// ---------------------------------------------------------------------------
// 7b) softmax rows of S. Applies per-d l2norm scale (knrm) first.
//     mode 0: softmax(S*knrm*temp[h]); mode 1: double softmax.
//     Writes attn as bf16 to Sb (consumed by MFMA PV).
// ---------------------------------------------------------------------------
__global__ __launch_bounds__(128) void chan_softmax_kernel(const float* __restrict__ Sg,
                                                           const float* __restrict__ knsq,
                                                           const float* __restrict__ temp,
                                                           bf16* __restrict__ Sb,
                                                           int mode) {
    __shared__ float knrm[96];
    int pair = blockIdx.x;
    int bi = pair >> 2, h = pair & 3;
    int tid = threadIdx.x;
    if (tid < 96)
        knrm[tid] = 1.0f / fmaxf(sqrtf(knsq[bi * CDIM + h * HDCH + tid]), 1e-12f);
    __syncthreads();
    if (tid >= 96) return;
    const float* Sr = Sg + (size_t)pair * 9216 + tid * 96;
    bf16* Ob = Sb + (size_t)pair * 9216 + tid * 96;
    if (mode == 0) {
        float tv = temp[h];
        float m = -1e30f;
        for (int d = 0; d < 96; ++d) m = fmaxf(m, Sr[d] * knrm[d] * tv);
        float s = 0.0f;
        for (int d = 0; d < 96; ++d) s += expf(Sr[d] * knrm[d] * tv - m);
        float inv = 1.0f / s;
        for (int d = 0; d < 96; ++d) Ob[d] = f2b(expf(Sr[d] * knrm[d] * tv - m) * inv);
    } else {
        const float RSQ = 0.10206207261596575f;  // 1/sqrt(96)
        float m1 = -1e30f;
        for (int d = 0; d < 96; ++d) m1 = fmaxf(m1, Sr[d] * knrm[d]);
        float s1 = 0.0f;
        for (int d = 0; d < 96; ++d) s1 += expf(Sr[d] * knrm[d] - m1);
        float inv1 = 1.0f / s1;
        float m2 = -1e30f;
        for (int d = 0; d < 96; ++d) {
            float l = Sr[d] * knrm[d];
            float a = 0.5f * l * RSQ + 0.5f * expf(l - m1) * inv1;
            m2 = fmaxf(m2, a);
        }
        float s2 = 0.0f;
        for (int d = 0; d < 96; ++d) {
            float l = Sr[d] * knrm[d];
            float a = 0.5f * l * RSQ + 0.5f * expf(l - m1) * inv1;
            s2 += expf(a - m2);
        }
        float inv2 = 1.0f / s2;
        for (int d = 0; d < 96; ++d) {
            float l = Sr[d] * knrm[d];
            float a = 0.5f * l * RSQ + 0.5f * expf(l - m1) * inv1;
            Ob[d] = f2b(expf(a - m2) * inv2);
        }
    }
}

// ---------------------------------------------------------------------------
// 7c) PV via MFMA: out[c,n] = sum_d attn[c,d]*V[d,n].
// ---------------------------------------------------------------------------
#define PVTN 256
__global__ __launch_bounds__(256) void chan_pv_mfma(const bf16* __restrict__ Sb,
                                                    const bf16* __restrict__ V,
                                                    bf16* __restrict__ out,
                                                    int n_len, int mode) {
    int nch = n_len / PVTN;
    int pair = blockIdx.x / nch, ck = blockIdx.x % nch;
    int bi = pair >> 2, h = pair & 3;
    int koff = h * HDCH;
    int tid = threadIdx.x;
    int wave = tid >> 6, lane = tid & 63;
    int lr = lane & 15, q = lane >> 4;
    const bf16* Ab = Sb + (size_t)pair * 9216;
    short8 af[6][3];
    #pragma unroll
    for (int i = 0; i < 6; ++i)
        #pragma unroll
        for (int kt = 0; kt < 3; ++kt)
            af[i][kt] = *(const short8*)(Ab + (i * 16 + lr) * 96 + kt * 32 + q * 8);
    const bf16* vb = V + (size_t)bi * n_len * 384 + koff;
    int nbase = ck * PVTN + wave * 16;
    #pragma unroll
    for (int s = 0; s < 4; ++s) {
        int n = nbase + s * 64 + lr;
        short8 bfr[3];
        #pragma unroll
        for (int kt = 0; kt < 3; ++kt)
            bfr[kt] = *(const short8*)(vb + (size_t)n * 384 + kt * 32 + q * 8);
        floatx4 acc[6] = {};
        #pragma unroll
        for (int kt = 0; kt < 3; ++kt)
            #pragma unroll
            for (int i = 0; i < 6; ++i)
                acc[i] = __builtin_amdgcn_mfma_f32_16x16x32_bf16(af[i][kt], bfr[kt], acc[i], 0, 0, 0);
        if (mode == 0) {
            bf16* op = out + (size_t)(bi * n_len + n) * CDIM + koff;
            #pragma unroll
            for (int i = 0; i < 6; ++i) {
                ushort4 o;
                o.x = f2b(acc[i][0]); o.y = f2b(acc[i][1]);
                o.z = f2b(acc[i][2]); o.w = f2b(acc[i][3]);
                *(ushort4*)(op + i * 16 + q * 4) = o;
            }
        } else {
            #pragma unroll
            for (int i = 0; i < 6; ++i) {
                int cb = i * 16 + q * 4;
                #pragma unroll
                for (int r = 0; r < 4; ++r)
                    out[(size_t)((h * 64 + bi) * HDCH + cb + r) * n_len + n] = f2b(acc[i][r]);
            }
        }
    }
}

// ---------------------------------------------------------------------------
// 8) Unfold gathers
// ---------------------------------------------------------------------------
__global__ __launch_bounds__(256) void unfold_cu_kernel(const float* __restrict__ xin,
                                                        bf16* __restrict__ cu) {
    int idx = blockIdx.x * 256 + threadIdx.x;    // 64*384*1024 total
    int b2 = idx / (CDIM * 1024);
    int rem = idx % (CDIM * 1024);
    int ch = rem >> 10, blk = rem & 1023;
    int b = b2 >> 2, patch = b2 & 3;
    int y = ((blk >> 5) << 1) | (patch >> 1);
    int x = ((blk & 31) << 1) | (patch & 1);
    cu[idx] = f2b(xin[(size_t)(b * CDIM + ch) * NPIX + (y << 6) + x]);
}

__global__ __launch_bounds__(256) void unfold_xu_kernel(const bf16* __restrict__ x4,
                                                        const float* __restrict__ cw,
                                                        const float* __restrict__ cb,
                                                        bf16* __restrict__ xu) {
    int idx = blockIdx.x * 256 + threadIdx.x;
    int row = idx / CDIM, ch = idx % CDIM;
    int b2 = row >> 10, blk = row & 1023;
    int b = b2 >> 2, patch = b2 & 3;
    int y = ((blk >> 5) << 1) | (patch >> 1);
    int x = ((blk & 31) << 1) | (patch & 1);
    xu[idx] = f2b(b2f(x4[(size_t)(b * NPIX + (y << 6) + x) * CDIM + ch]) * cw[ch] + cb[ch]);
}

// ---------------------------------------------------------------------------
// 9) out[b,c,p] = inp[b,c,p] + gamma[c] * final[(b*4096+p), c]  (fp32 out)
// ---------------------------------------------------------------------------
__global__ void out_kernel(const float* __restrict__ xin, const bf16* __restrict__ fin,
                           const float* __restrict__ gamma, float* __restrict__ outp) {
    __shared__ float t[32][33];
    int c0 = blockIdx.x * 32, p0 = blockIdx.y * 32, b = blockIdx.z;
    int tx = threadIdx.x, ty = threadIdx.y;
    #pragma unroll
    for (int k = 0; k < 4; ++k) {
        int pl = ty + k * 8;
        t[pl][tx] = b2f(fin[(size_t)(b * NPIX + p0 + pl) * CDIM + c0 + tx]);
    }
    __syncthreads();
    #pragma unroll
    for (int k = 0; k < 4; ++k) {
        int cl = ty + k * 8;
        size_t addr = (size_t)(b * CDIM + c0 + cl) * NPIX + p0 + tx;
        outp[addr] = xin[addr] + gamma[c0 + cl] * t[tx][cl];
    }
}

// ---------------------------------------------------------------------------
extern "C" void kernel_launch(void* const* d_in, const int* in_sizes, int n_in,
                              void* d_out, int out_size, void* d_ws, size_t ws_size,
                              hipStream_t stream) {
    (void)in_sizes; (void)n_in; (void)out_size; (void)ws_size;
    const float* x         = (const float*)d_in[0];
    const float* convs_w   = (const float*)d_in[1];
    const float* convs_b   = (const float*)d_in[2];
    const float* pos_w     = (const float*)d_in[3];
    const float* pos_b     = (const float*)d_in[4];
    const float* ln_xca_w  = (const float*)d_in[5];
    const float* ln_xca_b  = (const float*)d_in[6];
    const float* gamma_xca = (const float*)d_in[7];
    const float* xca_temp  = (const float*)d_in[8];
    const float* xca_kv_w  = (const float*)d_in[9];
    const float* xca_kv_b  = (const float*)d_in[10];
    const float* xca_proj_w= (const float*)d_in[11];
    const float* xca_proj_b= (const float*)d_in[12];
    const float* conv_out_w= (const float*)d_in[13];
    const float* conv_out_b= (const float*)d_in[14];
    const float* wa_kv_w   = (const float*)d_in[15];
    const float* wa_kv_b   = (const float*)d_in[16];
    const float* wa_proj_w = (const float*)d_in[17];
    const float* wa_proj_b = (const float*)d_in[18];
    const float* ln_w      = (const float*)d_in[19];
    const float* ln_b      = (const float*)d_in[20];
    const float* pw1_w     = (const float*)d_in[21];
    const float* pw1_b     = (const float*)d_in[22];
    const float* pw2_w     = (const float*)d_in[23];
    const float* pw2_b     = (const float*)d_in[24];
    const float* gamma     = (const float*)d_in[25];
    float* out = (float*)d_out;

    // Workspace: bf16 pools + fp32 accumulators. Total ~216 MiB (unchanged).
    bf16* pos = (bf16*)d_ws;                 // 1,572,864 elems
    bf16* P1  = pos + 1572864;               // 25,165,824 elems
    bf16* P2  = P1 + 25165824;               // 25,165,824 elems
    bf16* P3  = P2 + 25165824;               // 50,331,648 elems (KT | V during attn)
    float* knsq    = (float*)(P3 + 50331648);// 6,144  (xca)
    float* knsq_wa = knsq + 6144;            // 24,576 (wa)
    float* S_xca   = knsq_wa + 24576;        // 64*9216   = 589,824
    float* S_wa    = S_xca + 589824;         // 256*9216  = 2,359,296

    // bf16 weight staging, inside the pos pool:
    bf16* wbufA = pos + 589824;              // capacity 983,040 elems
    bf16* wbufB = pos;                       // free after xca chan_pv (pw2 weights)

    // zero knsq + knsq_wa + S_xca + S_wa = 2,979,840 floats = 11640 * 256
    zero_kernel<<<11640, 256, 0, stream>>>(knsq);

    // pos embedding
    pos_kernel<<<4096, 128, 0, stream>>>(pos_w, pos_b, pos);

    // multi-scale depthwise conv chain -> P1 (xcat)
    dwconv_kernel<<<NBATCH * 96, 256, 0, stream>>>(x,   0, nullptr, 0,  convs_w,        convs_b,       P1, 0);
    dwconv_kernel<<<NBATCH * 96, 256, 0, stream>>>(x,  96, P1,      0,  convs_w + 864,  convs_b + 96,  P1, 96);
    dwconv_kernel<<<NBATCH * 96, 256, 0, stream>>>(x, 192, P1,     96,  convs_w + 1728, convs_b + 192, P1, 192);
    convert_last_kernel<<<6144, 256, 0, stream>>>(x, P1);

    // x3 = transpose(xcat) + pos -> P2
    x3_kernel<<<dim3(12, 128, NBATCH), dim3(32, 8), 0, stream>>>(P1, pos, P2);

    // XCA: LN -> kv (KT|V split) -> knorm -> MFMA attention -> proj(+res*gamma_xca) = x4
    ln_kernel<<<NROWS, 128, 0, stream>>>(P2, ln_xca_w, ln_xca_b, P1, 0);
    wcvt_kernel<<<288, 256, 0, stream>>>(xca_kv_w, wbufA, 73728);        // 768x384
    mfma_gemm_kernel<<<dim3(512, 6), 256, 0, stream>>>(P1, wbufA, xca_kv_b, P3,
                                                       NROWS, 768, 384, 3, nullptr, nullptr, 12);
    knormsq2_kernel<<<6144, 256, 0, stream>>>(P3, knsq, 4096);
    chan_qk_mfma<<<512, 256, 0, stream>>>(x, nullptr, P3, S_xca, 4096, 8, 0);
    chan_softmax_kernel<<<64, 128, 0, stream>>>(S_xca, knsq, xca_temp, pos, 0);      // attn bf16 -> pos[0:589824]
    chan_pv_mfma<<<1024, 256, 0, stream>>>(pos, P3 + KVHALF, P1, 4096, 0);
    wcvt_kernel<<<144, 256, 0, stream>>>(xca_proj_w, wbufA, 36864);      // 384x384
    mfma_gemm_kernel<<<dim3(512, 3), 256, 0, stream>>>(P1, wbufA, xca_proj_b, P3,
                                                       NROWS, 384, 384, 2, P2, gamma_xca, 0);  // x4 -> P3 lo

    // window attention
    unfold_cu_kernel<<<98304, 256, 0, stream>>>(x, P2);                                 // cu
    unfold_xu_kernel<<<98304, 256, 0, stream>>>(P3, conv_out_w, conv_out_b, P1);        // xu
    wcvt_kernel<<<288, 256, 0, stream>>>(wa_kv_w, wbufA, 73728);         // 768x384
    mfma_gemm_kernel<<<dim3(512, 6), 256, 0, stream>>>(P1, wbufA, wa_kv_b, P3,
                                                       NROWS, 768, 384, 3, nullptr, nullptr, 10);
    knormsq2_kernel<<<24576, 256, 0, stream>>>(P3, knsq_wa, 1024);
    chan_qk_mfma<<<512, 256, 0, stream>>>(nullptr, P2, P3, S_wa, 1024, 2, 1);
    chan_softmax_kernel<<<256, 128, 0, stream>>>(S_wa, knsq_wa, nullptr, P2, 1);        // attn bf16 -> P2 (cu dead)
    chan_pv_mfma<<<1024, 256, 0, stream>>>(P2, P3 + KVHALF, P1, 1024, 1);               // Xpre
    wcvt_kernel<<<144, 256, 0, stream>>>(wa_proj_w, wbufA, 36864);       // 384x384
    mfma_gemm_kernel<<<dim3(512, 3), 256, 0, stream>>>(P1, wbufA, wa_proj_b, P2,
                                                       NROWS, 384, 384, 0, nullptr, nullptr, 0);  // Y

    // MLP: LN(fold remap) -> pw1(gelu) -> pw2, chunked 2x32768 rows
    // (P3 holds exactly 32768*1536 elems for the GELU intermediate)
    ln_kernel<<<NROWS, 128, 0, stream>>>(P2, ln_w, ln_b, P1, 1);
    wcvt_kernel<<<576, 256, 0, stream>>>(pw1_w, wbufA, 147456);          // 1536x384
    wcvt_kernel<<<576, 256, 0, stream>>>(pw2_w, wbufB, 147456);          // 384x1536
    for (int ch = 0; ch < 2; ++ch) {
        mfma_gemm_kernel<<<dim3(256, 12), 256, 0, stream>>>(P1 + (size_t)ch * 32768 * 384, wbufA, pw1_b,
                                                            P3, 32768, 1536, 384, 1, nullptr, nullptr, 0);
        mfma_gemm_kernel<<<dim3(256, 3), 256, 0, stream>>>(P3, wbufB, pw2_b,
                                                           P2 + (size_t)ch * 32768 * 384, 32768, 384, 1536,
                                                           0, nullptr, nullptr, 0);
    }

    // out = inp + gamma * final (transpose back to NCHW)
    out_kernel<<<dim3(12, 128, NBATCH), dim3(32, 8), 0, stream>>>(x, P2, gamma, out);
}

// Round 6
// 1263.292 us; speedup vs baseline: 1.0907x; 1.0907x over previous
//
#include <hip/hip_runtime.h>
#include <math.h>

// Problem constants
#define NBATCH 16
#define CDIM   384
#define NPIX   4096      // H*W = 64*64
#define HDCH   96        // channels per head
#define NROWS  65536     // NBATCH*NPIX
#define KVHALF 25165824  // 65536*384 = elems in KT (== elems in V)

typedef unsigned short bf16;
typedef __attribute__((ext_vector_type(8))) short short8;
typedef __attribute__((ext_vector_type(4))) float floatx4;

union S8U { short8 v; bf16 u[8]; };

__device__ __forceinline__ float b2f(bf16 u) {
    union { unsigned int i; float f; } c; c.i = ((unsigned int)u) << 16; return c.f;
}
__device__ __forceinline__ bf16 f2b(float f) {
    union { float f; unsigned int i; } c; c.f = f;
    unsigned int r = (c.i + 0x7FFFu + ((c.i >> 16) & 1u)) >> 16;
    return (bf16)r;
}

// async global->LDS, 16B per lane. LDS dest is wave-uniform base + lane*16.
__device__ __forceinline__ void gload16(const bf16* g, bf16* l) {
    __builtin_amdgcn_global_load_lds(
        (const __attribute__((address_space(1))) unsigned int*)g,
        (__attribute__((address_space(3))) unsigned int*)l, 16, 0, 0);
}

// ---------------------------------------------------------------------------
// 0) zero scratch accumulators
// ---------------------------------------------------------------------------
__global__ __launch_bounds__(256) void zero_kernel(float* __restrict__ p) {
    p[blockIdx.x * 256 + threadIdx.x] = 0.0f;
}

// 0b) convert fp32 weights -> bf16 (float4/ushort4 vectorized)
__global__ __launch_bounds__(256) void wcvt_kernel(const float* __restrict__ w,
                                                   bf16* __restrict__ o, int n4) {
    int i = blockIdx.x * 256 + threadIdx.x;
    if (i < n4) {
        float4 v = ((const float4*)w)[i];
        ushort4 u;
        u.x = f2b(v.x); u.y = f2b(v.y); u.z = f2b(v.z); u.w = f2b(v.w);
        ((ushort4*)o)[i] = u;
    }
}

// ---------------------------------------------------------------------------
// 1) Fourier positional embedding: pos[n, c] (bf16 out)
// ---------------------------------------------------------------------------
__global__ __launch_bounds__(128) void pos_kernel(const float* __restrict__ pos_w,
                                                  const float* __restrict__ pos_b,
                                                  bf16* __restrict__ pos) {
    __shared__ float feat[64];
    int n = blockIdx.x;
    int yi = n >> 6, xi = n & 63;
    int tid = threadIdx.x;
    if (tid < 64) {
        int j = tid & 31;
        int isx = tid >= 32;
        float base = (float)((isx ? xi : yi) + 1);
        float val = base / (64.0f + 1e-6f) * 6.283185307179586f;
        float e = (float)(2 * (j >> 1)) / 32.0f;
        float dt = powf(10000.0f, e);
        float a = val / dt;
        feat[isx * 32 + j] = (j & 1) ? cosf(a) : sinf(a);
    }
    __syncthreads();
    for (int c = tid; c < CDIM; c += 128) {
        float s = pos_b[c];
        const float* wr = pos_w + c * 64;
        #pragma unroll 16
        for (int j = 0; j < 64; ++j) s += feat[j] * wr[j];
        pos[n * CDIM + c] = f2b(s);
    }
}

// ---------------------------------------------------------------------------
// 2) Depthwise 3x3 conv (pad 1). xin fp32 chunk (+ prev bf16 chunk), out bf16.
// ---------------------------------------------------------------------------
__global__ __launch_bounds__(256) void dwconv_kernel(const float* __restrict__ xin, int in_ch0,
                                                     const bf16* __restrict__ prev, int prev_ch0,
                                                     const float* __restrict__ w,
                                                     const float* __restrict__ bias,
                                                     bf16* __restrict__ out, int out_ch0) {
    __shared__ float tile[66][66];
    int b = blockIdx.x / 96, c = blockIdx.x % 96;
    const float* ip = xin + (b * CDIM + in_ch0 + c) * NPIX;
    const bf16* pp = prev ? prev + (b * CDIM + prev_ch0 + c) * NPIX : nullptr;
    int tid = threadIdx.x;
    for (int i = tid; i < 66 * 66; i += 256) {
        int yy = i / 66 - 1, xx = i % 66 - 1;
        float v = 0.0f;
        if (yy >= 0 && yy < 64 && xx >= 0 && xx < 64) {
            v = ip[yy * 64 + xx];
            if (pp) v += b2f(pp[yy * 64 + xx]);
        }
        tile[i / 66][i % 66] = v;
    }
    __syncthreads();
    float wc[9];
    #pragma unroll
    for (int j = 0; j < 9; ++j) wc[j] = w[c * 9 + j];
    float b0 = bias[c];
    bf16* op = out + (b * CDIM + out_ch0 + c) * NPIX;
    for (int p = tid; p < NPIX; p += 256) {
        int y = p >> 6, x = p & 63;
        float a = b0;
        #pragma unroll
        for (int dy = 0; dy < 3; ++dy)
            #pragma unroll
            for (int dx = 0; dx < 3; ++dx)
                a += tile[y + dy][x + dx] * wc[dy * 3 + dx];
        op[p] = f2b(a);
    }
}

// convert channels [288:384) of x (fp32) into xcat (bf16)
__global__ __launch_bounds__(256) void convert_last_kernel(const float* __restrict__ x,
                                                           bf16* __restrict__ xcat) {
    int idx = blockIdx.x * 256 + threadIdx.x;   // 16*96*4096/4 = 1,572,864 threads
    int b = idx / (96 * 1024);
    int rem = idx % (96 * 1024);
    const float4* src = (const float4*)(x + (b * CDIM + 288) * NPIX);
    float4 v = src[rem];
    ushort4 o;
    o.x = f2b(v.x); o.y = f2b(v.y); o.z = f2b(v.z); o.w = f2b(v.w);
    ((ushort4*)(xcat + (b * CDIM + 288) * NPIX))[rem] = o;
}

// ---------------------------------------------------------------------------
// 3) x3[b,n,c] = xcat[b,c,n] + pos[n,c]   (LDS 32x32 transpose, bf16 io)
// ---------------------------------------------------------------------------
__global__ void x3_kernel(const bf16* __restrict__ xcat, const bf16* __restrict__ pos,
                          bf16* __restrict__ x3) {
    __shared__ float t[32][33];
    int c0 = blockIdx.x * 32, n0 = blockIdx.y * 32, b = blockIdx.z;
    int tx = threadIdx.x, ty = threadIdx.y;
    #pragma unroll
    for (int k = 0; k < 4; ++k) {
        int cl = ty + k * 8;
        t[cl][tx] = b2f(xcat[(b * CDIM + c0 + cl) * NPIX + n0 + tx]);
    }
    __syncthreads();
    #pragma unroll
    for (int k = 0; k < 4; ++k) {
        int nl = ty + k * 8;
        x3[(b * NPIX + n0 + nl) * CDIM + c0 + tx] =
            f2b(t[tx][nl] + b2f(pos[(n0 + nl) * CDIM + c0 + tx]));
    }
}

// ---------------------------------------------------------------------------
// 4) Row LayerNorm over C=384, bf16 io. map=1: fold-remap source row.
// ---------------------------------------------------------------------------
__global__ __launch_bounds__(128) void ln_kernel(const bf16* __restrict__ in,
                                                 const float* __restrict__ w,
                                                 const float* __restrict__ b,
                                                 bf16* __restrict__ out, int map) {
    int r = blockIdx.x;
    int src = r;
    if (map == 1) {
        int bb = r >> 12;
        int p = r & 4095;
        int y = p >> 6, x = p & 63;
        int patch = ((y & 1) << 1) | (x & 1);
        int blk = ((y >> 1) << 5) | (x >> 1);
        src = ((bb << 2) + patch) * 1024 + blk;
    }
    const bf16* row = in + src * CDIM;
    int tid = threadIdx.x;
    float v[3];
    float s1 = 0.0f, s2 = 0.0f;
    #pragma unroll
    for (int i = 0; i < 3; ++i) {
        v[i] = b2f(row[tid + i * 128]);
        s1 += v[i];
        s2 += v[i] * v[i];
    }
    __shared__ float r1[128], r2[128];
    r1[tid] = s1; r2[tid] = s2;
    __syncthreads();
    for (int off = 64; off > 0; off >>= 1) {
        if (tid < off) { r1[tid] += r1[tid + off]; r2[tid] += r2[tid + off]; }
        __syncthreads();
    }
    float mean = r1[0] * (1.0f / 384.0f);
    float var = fmaxf(r2[0] * (1.0f / 384.0f) - mean * mean, 0.0f);
    float rstd = rsqrtf(var + 1e-6f);
    #pragma unroll
    for (int i = 0; i < 3; ++i) {
        int c = tid + i * 128;
        out[r * CDIM + c] = f2b((v[i] - mean) * rstd * w[c] + b[c]);
    }
}

// ---------------------------------------------------------------------------
// 5) MFMA GEMM: C[M,Nout] = epi(A[M,K](bf16) @ W[Nout,K]^T(bf16) + bias)
//    128x128 tile, BK=32, 4 waves, 16x16x32 bf16 MFMA.
//    3-buffer depth-2 software pipeline (measured best: deeper = occupancy loss):
//      iter t: STAGE(buf[(t+2)%3]) ; compute buf[t%3] ; vmcnt(4) ; s_barrier
//    XCD-chunked swizzle (T1): flat dispatch d -> wg=(d%8)*(nwg/8)+d/8, then
//    x-major/y-inner decompose so each A panel is read ny times consecutively
//    on ONE XCD (L2-hot) and fetched from HBM exactly once.
//    Staging: global_load_lds width-16, linear LDS [128][32] with both-sides
//    involution swizzle: phys chunk = logical chunk XOR ((row>>1)&3).
//    mode 0: plain   mode 1: exact GELU   mode 2: res(bf16) + scalevec[c]*(.)
//    mode 3: kv-split — cols<384 write transposed KT[(row>>nlog2)*384+col][row&mask]
//            AND fused knormsq: atomicAdd per-column sum of squares into knsq_out;
//            cols>=384 write V at C+KVHALF, [row][col-384]
// ---------------------------------------------------------------------------
__global__ __launch_bounds__(256) void mfma_gemm_kernel(const bf16* __restrict__ A,
                                                        const bf16* __restrict__ W,
                                                        const float* __restrict__ bias,
                                                        bf16* __restrict__ C,
                                                        int M, int Nout, int K, int mode,
                                                        const bf16* __restrict__ res,
                                                        const float* __restrict__ scalevec,
                                                        int nlog2,
                                                        float* __restrict__ knsq_out) {
    __shared__ bf16 As[3][128][32];   // 24 KB
    __shared__ bf16 Bs[3][128][32];   // 24 KB
    // --- XCD-chunked swizzle + panel-major decomposition ---
    int nx = gridDim.x, ny = gridDim.y;
    int d = blockIdx.x + nx * blockIdx.y;     // flat dispatch id (x fastest)
    int nwg = nx * ny;
    int xt, yt;
    if ((nwg & 7) == 0) {
        int cpx = nwg >> 3;
        int wg = (d & 7) * cpx + (d >> 3);    // contiguous range per XCD
        xt = wg / ny;                         // A-panel index (owned by one XCD)
        yt = wg % ny;
    } else {
        xt = blockIdx.x; yt = blockIdx.y;
    }
    int m0 = xt * 128;
    int n0 = yt * 128;
    int tid = threadIdx.x;
    int wave = tid >> 6, lane = tid & 63;
    int wm = (wave & 1) * 64;
    int wn = (wave >> 1) * 64;
    int quad = lane >> 4;
    int lrow = lane & 15;

    // --- staging address decomposition (per-thread, loop-invariant) ---
    // physical byte within 8KB tile: p = call*4096 + wave*1024 + lane*16
    // logical byte o = p ^ (((p>>7)&3)<<4); row = o>>6, chunk=(o>>4)&3
    int p0b = wave * 1024 + lane * 16;
    int o0 = p0b ^ (((p0b >> 7) & 3) << 4);
    int r0 = o0 >> 6;
    int ch0 = (o0 >> 4) & 3;

    const bf16* aSrc0 = A + (size_t)(m0 + r0) * K + ch0 * 8;
    const bf16* aSrc1 = A + (size_t)(m0 + r0 + 64) * K + ch0 * 8;
    const bf16* bSrc0 = W + (size_t)(n0 + r0) * K + ch0 * 8;
    const bf16* bSrc1 = W + (size_t)(n0 + r0 + 64) * K + ch0 * 8;
    bf16* lA0 = &As[0][0][0] + wave * 512;          // wave-uniform LDS bases (buffer 0)
    bf16* lA1 = &As[0][0][0] + 2048 + wave * 512;
    bf16* lB0 = &Bs[0][0][0] + wave * 512;
    bf16* lB1 = &Bs[0][0][0] + 2048 + wave * 512;

    // swizzled read column (elems)
    int rcol = (quad ^ ((lrow >> 1) & 3)) * 8;
    int NT = K >> 5;

#define STAGE(bi_, t_) do { int _off = (bi_) * 4096; int _kk = (t_) * 32; \
        gload16(aSrc0 + _kk, lA0 + _off); \
        gload16(aSrc1 + _kk, lA1 + _off); \
        gload16(bSrc0 + _kk, lB0 + _off); \
        gload16(bSrc1 + _kk, lB1 + _off); } while (0)

    floatx4 acc[4][4] = {};

    // prologue: two tiles in flight, wait for tile 0 only
    STAGE(0, 0);
    STAGE(1, 1);
    asm volatile("s_waitcnt vmcnt(4)" ::: "memory");
    __builtin_amdgcn_s_barrier();
    __builtin_amdgcn_sched_barrier(0);

    for (int t = 0; t < NT; ++t) {
        int bi = t % 3;
        if (t + 2 < NT) STAGE((t + 2) % 3, t + 2);   // safe: readers of this buf passed barrier(t-1)
        short8 af[4], bfr[4];
        #pragma unroll
        for (int i = 0; i < 4; ++i)
            af[i] = *(const short8*)(&As[bi][wm + i * 16 + lrow][rcol]);
        #pragma unroll
        for (int j = 0; j < 4; ++j)
            bfr[j] = *(const short8*)(&Bs[bi][wn + j * 16 + lrow][rcol]);
        #pragma unroll
        for (int i = 0; i < 4; ++i)
            #pragma unroll
            for (int j = 0; j < 4; ++j)
                acc[i][j] = __builtin_amdgcn_mfma_f32_16x16x32_bf16(af[i], bfr[j], acc[i][j], 0, 0, 0);
        if (t + 1 < NT) {
            if (t + 2 < NT) asm volatile("s_waitcnt vmcnt(4)" ::: "memory");  // t+1 landed, t+2 in flight
            else            asm volatile("s_waitcnt vmcnt(0)" ::: "memory");  // last prefetch landed
            __builtin_amdgcn_s_barrier();
            __builtin_amdgcn_sched_barrier(0);
        }
    }
#undef STAGE

    if (mode == 3) {
        int nmask = (1 << nlog2) - 1;
        // block never straddles a batch group (128 | 2^nlog2), so bb uniform per i-group
        #pragma unroll
        for (int j = 0; j < 4; ++j) {
            int col = n0 + wn + j * 16 + lrow;
            float bv = bias[col];
            if (col < 384) {
                float ss = 0.0f;
                #pragma unroll
                for (int i = 0; i < 4; ++i) {
                    int rowb = m0 + wm + i * 16 + quad * 4;
                    int bb = rowb >> nlog2, tok = rowb & nmask;
                    float v0 = acc[i][j][0] + bv;
                    float v1 = acc[i][j][1] + bv;
                    float v2 = acc[i][j][2] + bv;
                    float v3 = acc[i][j][3] + bv;
                    ss += v0 * v0 + v1 * v1 + v2 * v2 + v3 * v3;
                    ushort4 o;
                    o.x = f2b(v0); o.y = f2b(v1); o.z = f2b(v2); o.w = f2b(v3);
                    *(ushort4*)(C + ((((size_t)bb * 384 + col) << nlog2) | (size_t)tok)) = o;
                }
                int bb0 = (m0 + wm) >> nlog2;
                atomicAdd(&knsq_out[bb0 * CDIM + col], ss);
            } else {
                #pragma unroll
                for (int i = 0; i < 4; ++i) {
                    int rowb = m0 + wm + i * 16 + quad * 4;
                    bf16* vp = C + KVHALF + (size_t)rowb * 384 + (col - 384);
                    #pragma unroll
                    for (int r = 0; r < 4; ++r)
                        vp[(size_t)r * 384] = f2b(acc[i][j][r] + bv);
                }
            }
        }
        return;
    }

    // epilogue: D row = quad*4+reg (within 16-tile), col = lrow
    #pragma unroll
    for (int i = 0; i < 4; ++i) {
        int rowb = m0 + wm + i * 16 + quad * 4;
        #pragma unroll
        for (int j = 0; j < 4; ++j) {
            int col = n0 + wn + j * 16 + lrow;
            float bv = bias[col];
            #pragma unroll
            for (int r = 0; r < 4; ++r) {
                int row = rowb + r;
                float v = acc[i][j][r] + bv;
                if (mode == 1) {
                    v = 0.5f * v * (1.0f + erff(v * 0.70710678118654752f));
                } else if (mode == 2) {
                    v = b2f(res[(size_t)row * Nout + col]) + scalevec[col] * v;
                }
                C[(size_t)row * Nout + col] = f2b(v);
            }
        }
    }
}

// ---------------------------------------------------------------------------
// 7a) S accumulate via MFMA: S[pair,c,d] += sum_{n in chunk} Q[c,n]*K[d,n]
// ---------------------------------------------------------------------------
__global__ __launch_bounds__(256) void chan_qk_mfma(const float* __restrict__ qf,
                                                    const bf16* __restrict__ qb,
                                                    const bf16* __restrict__ KT,
                                                    float* __restrict__ Sg,
                                                    int n_len, int nchunks, int mode) {
    int pair = blockIdx.x / nchunks, ck = blockIdx.x % nchunks;
    int bi = pair >> 2, h = pair & 3;
    int koff = h * HDCH;
    int chunk = n_len / nchunks;
    int nbeg = ck * chunk;
    int tid = threadIdx.x;
    int wave = tid >> 6, lane = tid & 63;
    int lr = lane & 15, q = lane >> 4;
    int c0 = (wave & 1) * 48;
    int d0 = (wave >> 1) * 48;
    floatx4 acc[3][3] = {};
    const size_t qbase = (size_t)(bi * CDIM + koff) * n_len;
    const bf16* kbase = KT + (size_t)(bi * CDIM + koff) * n_len;
    for (int nn = 0; nn < chunk; nn += 32) {
        int n0 = nbeg + nn + q * 8;
        short8 af[3], bfr[3];
        if (mode == 0) {
            #pragma unroll
            for (int i = 0; i < 3; ++i) {
                const float* qp = qf + qbase + (size_t)(c0 + i * 16 + lr) * n_len + n0;
                float4 f0 = *(const float4*)qp;
                float4 f1 = *(const float4*)(qp + 4);
                S8U t;
                t.u[0] = f2b(f0.x); t.u[1] = f2b(f0.y); t.u[2] = f2b(f0.z); t.u[3] = f2b(f0.w);
                t.u[4] = f2b(f1.x); t.u[5] = f2b(f1.y); t.u[6] = f2b(f1.z); t.u[7] = f2b(f1.w);
                af[i] = t.v;
            }
        } else {
            #pragma unroll
            for (int i = 0; i < 3; ++i)
                af[i] = *(const short8*)(qb + qbase + (size_t)(c0 + i * 16 + lr) * n_len + n0);
        }
        #pragma unroll
        for (int j = 0; j < 3; ++j)
            bfr[j] = *(const short8*)(kbase + (size_t)(d0 + j * 16 + lr) * n_len + n0);
        #pragma unroll
        for (int i = 0; i < 3; ++i)
            #pragma unroll
            for (int j = 0; j < 3; ++j)
                acc[i][j] = __builtin_amdgcn_mfma_f32_16x16x32_bf16(af[i], bfr[j], acc[i][j], 0, 0, 0);
    }
    float* Sp = Sg + (size_t)pair * 9216;
    #pragma unroll
    for (int i = 0; i < 3; ++i) {
        int rowb = c0 + i * 16 + q * 4;
        #pragma unroll
        for (int j = 0; j < 3; ++j) {
            int col = d0 + j * 16 + lr;
            #pragma unroll
            for (int r = 0; r < 4; ++r)
                atomicAdd(&Sp[(rowb + r) * 96 + col], acc[i][j][r]);
        }
    }
}

// ---------------------------------------------------------------------------
// 7b) softmax rows of S. Applies per-d l2norm scale (knrm) first.
//     mode 0: softmax(S*knrm*temp[h]); mode 1: double softmax.
//     Writes attn as bf16 to Sb (consumed by MFMA PV).
// ---------------------------------------------------------------------------
__global__ __launch_bounds__(128) void chan_softmax_kernel(const float* __restrict__ Sg,
                                                           const float* __restrict__ knsq,
                                                           const float* __restrict__ temp,
                                                           bf16* __restrict__ Sb,
                                                           int mode) {
    __shared__ float knrm[96];
    int pair = blockIdx.x;
    int bi = pair >> 2, h = pair & 3;
    int tid = threadIdx.x;
    if (tid < 96)
        knrm[tid] = 1.0f / fmaxf(sqrtf(knsq[bi * CDIM + h * HDCH + tid]), 1e-12f);
    __syncthreads();
    if (tid >= 96) return;
    const float* Sr = Sg + (size_t)pair * 9216 + tid * 96;
    bf16* Ob = Sb + (size_t)pair * 9216 + tid * 96;
    if (mode == 0) {
        float tv = temp[h];
        float m = -1e30f;
        for (int d = 0; d < 96; ++d) m = fmaxf(m, Sr[d] * knrm[d] * tv);
        float s = 0.0f;
        for (int d = 0; d < 96; ++d) s += expf(Sr[d] * knrm[d] * tv - m);
        float inv = 1.0f / s;
        for (int d = 0; d < 96; ++d) Ob[d] = f2b(expf(Sr[d] * knrm[d] * tv - m) * inv);
    } else {
        const float RSQ = 0.10206207261596575f;  // 1/sqrt(96)
        float m1 = -1e30f;
        for (int d = 0; d < 96; ++d) m1 = fmaxf(m1, Sr[d] * knrm[d]);
        float s1 = 0.0f;
        for (int d = 0; d < 96; ++d) s1 += expf(Sr[d] * knrm[d] - m1);
        float inv1 = 1.0f / s1;
        float m2 = -1e30f;
        for (int d = 0; d < 96; ++d) {
            float l = Sr[d] * knrm[d];
            float a = 0.5f * l * RSQ + 0.5f * expf(l - m1) * inv1;
            m2 = fmaxf(m2, a);
        }
        float s2 = 0.0f;
        for (int d = 0; d < 96; ++d) {
            float l = Sr[d] * knrm[d];
            float a = 0.5f * l * RSQ + 0.5f * expf(l - m1) * inv1;
            s2 += expf(a - m2);
        }
        float inv2 = 1.0f / s2;
        for (int d = 0; d < 96; ++d) {
            float l = Sr[d] * knrm[d];
            float a = 0.5f * l * RSQ + 0.5f * expf(l - m1) * inv1;
            Ob[d] = f2b(expf(a - m2) * inv2);
        }
    }
}

// ---------------------------------------------------------------------------
// 7c) PV via MFMA: out[c,n] = sum_d attn[c,d]*V[d,n].
// ---------------------------------------------------------------------------
#define PVTN 256
__global__ __launch_bounds__(256) void chan_pv_mfma(const bf16* __restrict__ Sb,
                                                    const bf16* __restrict__ V,
                                                    bf16* __restrict__ out,
                                                    int n_len, int mode) {
    int nch = n_len / PVTN;
    int pair = blockIdx.x / nch, ck = blockIdx.x % nch;
    int bi = pair >> 2, h = pair & 3;
    int koff = h * HDCH;
    int tid = threadIdx.x;
    int wave = tid >> 6, lane = tid & 63;
    int lr = lane & 15, q = lane >> 4;
    const bf16* Ab = Sb + (size_t)pair * 9216;
    short8 af[6][3];
    #pragma unroll
    for (int i = 0; i < 6; ++i)
        #pragma unroll
        for (int kt = 0; kt < 3; ++kt)
            af[i][kt] = *(const short8*)(Ab + (i * 16 + lr) * 96 + kt * 32 + q * 8);
    const bf16* vb = V + (size_t)bi * n_len * 384 + koff;
    int nbase = ck * PVTN + wave * 16;
    #pragma unroll
    for (int s = 0; s < 4; ++s) {
        int n = nbase + s * 64 + lr;
        short8 bfr[3];
        #pragma unroll
        for (int kt = 0; kt < 3; ++kt)
            bfr[kt] = *(const short8*)(vb + (size_t)n * 384 + kt * 32 + q * 8);
        floatx4 acc[6] = {};
        #pragma unroll
        for (int kt = 0; kt < 3; ++kt)
            #pragma unroll
            for (int i = 0; i < 6; ++i)
                acc[i] = __builtin_amdgcn_mfma_f32_16x16x32_bf16(af[i][kt], bfr[kt], acc[i], 0, 0, 0);
        if (mode == 0) {
            bf16* op = out + (size_t)(bi * n_len + n) * CDIM + koff;
            #pragma unroll
            for (int i = 0; i < 6; ++i) {
                ushort4 o;
                o.x = f2b(acc[i][0]); o.y = f2b(acc[i][1]);
                o.z = f2b(acc[i][2]); o.w = f2b(acc[i][3]);
                *(ushort4*)(op + i * 16 + q * 4) = o;
            }
        } else {
            #pragma unroll
            for (int i = 0; i < 6; ++i) {
                int cb = i * 16 + q * 4;
                #pragma unroll
                for (int r = 0; r < 4; ++r)
                    out[(size_t)((h * 64 + bi) * HDCH + cb + r) * n_len + n] = f2b(acc[i][r]);
            }
        }
    }
}

// ---------------------------------------------------------------------------
// 8) Unfold gathers
// ---------------------------------------------------------------------------
__global__ __launch_bounds__(256) void unfold_cu_kernel(const float* __restrict__ xin,
                                                        bf16* __restrict__ cu) {
    int idx = blockIdx.x * 256 + threadIdx.x;    // 64*384*1024 total
    int b2 = idx / (CDIM * 1024);
    int rem = idx % (CDIM * 1024);
    int ch = rem >> 10, blk = rem & 1023;
    int b = b2 >> 2, patch = b2 & 3;
    int y = ((blk >> 5) << 1) | (patch >> 1);
    int x = ((blk & 31) << 1) | (patch & 1);
    cu[idx] = f2b(xin[(size_t)(b * CDIM + ch) * NPIX + (y << 6) + x]);
}

__global__ __launch_bounds__(256) void unfold_xu_kernel(const bf16* __restrict__ x4,
                                                        const float* __restrict__ cw,
                                                        const float* __restrict__ cb,
                                                        bf16* __restrict__ xu) {
    int idx = blockIdx.x * 256 + threadIdx.x;
    int row = idx / CDIM, ch = idx % CDIM;
    int b2 = row >> 10, blk = row & 1023;
    int b = b2 >> 2, patch = b2 & 3;
    int y = ((blk >> 5) << 1) | (patch >> 1);
    int x = ((blk & 31) << 1) | (patch & 1);
    xu[idx] = f2b(b2f(x4[(size_t)(b * NPIX + (y << 6) + x) * CDIM + ch]) * cw[ch] + cb[ch]);
}

// ---------------------------------------------------------------------------
// 9) out[b,c,p] = inp[b,c,p] + gamma[c] * final[(b*4096+p), c]  (fp32 out)
// ---------------------------------------------------------------------------
__global__ void out_kernel(const float* __restrict__ xin, const bf16* __restrict__ fin,
                           const float* __restrict__ gamma, float* __restrict__ outp) {
    __shared__ float t[32][33];
    int c0 = blockIdx.x * 32, p0 = blockIdx.y * 32, b = blockIdx.z;
    int tx = threadIdx.x, ty = threadIdx.y;
    #pragma unroll
    for (int k = 0; k < 4; ++k) {
        int pl = ty + k * 8;
        t[pl][tx] = b2f(fin[(size_t)(b * NPIX + p0 + pl) * CDIM + c0 + tx]);
    }
    __syncthreads();
    #pragma unroll
    for (int k = 0; k < 4; ++k) {
        int cl = ty + k * 8;
        size_t addr = (size_t)(b * CDIM + c0 + cl) * NPIX + p0 + tx;
        outp[addr] = xin[addr] + gamma[c0 + cl] * t[tx][cl];
    }
}

// ---------------------------------------------------------------------------
extern "C" void kernel_launch(void* const* d_in, const int* in_sizes, int n_in,
                              void* d_out, int out_size, void* d_ws, size_t ws_size,
                              hipStream_t stream) {
    (void)in_sizes; (void)n_in; (void)out_size; (void)ws_size;
    const float* x         = (const float*)d_in[0];
    const float* convs_w   = (const float*)d_in[1];
    const float* convs_b   = (const float*)d_in[2];
    const float* pos_w     = (const float*)d_in[3];
    const float* pos_b     = (const float*)d_in[4];
    const float* ln_xca_w  = (const float*)d_in[5];
    const float* ln_xca_b  = (const float*)d_in[6];
    const float* gamma_xca = (const float*)d_in[7];
    const float* xca_temp  = (const float*)d_in[8];
    const float* xca_kv_w  = (const float*)d_in[9];
    const float* xca_kv_b  = (const float*)d_in[10];
    const float* xca_proj_w= (const float*)d_in[11];
    const float* xca_proj_b= (const float*)d_in[12];
    const float* conv_out_w= (const float*)d_in[13];
    const float* conv_out_b= (const float*)d_in[14];
    const float* wa_kv_w   = (const float*)d_in[15];
    const float* wa_kv_b   = (const float*)d_in[16];
    const float* wa_proj_w = (const float*)d_in[17];
    const float* wa_proj_b = (const float*)d_in[18];
    const float* ln_w      = (const float*)d_in[19];
    const float* ln_b      = (const float*)d_in[20];
    const float* pw1_w     = (const float*)d_in[21];
    const float* pw1_b     = (const float*)d_in[22];
    const float* pw2_w     = (const float*)d_in[23];
    const float* pw2_b     = (const float*)d_in[24];
    const float* gamma     = (const float*)d_in[25];
    float* out = (float*)d_out;

    // Workspace: bf16 pools + fp32 accumulators. Total ~216 MiB (unchanged).
    bf16* pos = (bf16*)d_ws;                 // 1,572,864 elems
    bf16* P1  = pos + 1572864;               // 25,165,824 elems
    bf16* P2  = P1 + 25165824;               // 25,165,824 elems
    bf16* P3  = P2 + 25165824;               // 50,331,648 elems (KT | V during attn)
    float* knsq    = (float*)(P3 + 50331648);// 6,144  (xca)
    float* knsq_wa = knsq + 6144;            // 24,576 (wa)
    float* S_xca   = knsq_wa + 24576;        // 64*9216   = 589,824
    float* S_wa    = S_xca + 589824;         // 256*9216  = 2,359,296

    // bf16 weight staging, inside the pos pool:
    bf16* wbufA = pos + 589824;              // capacity 983,040 elems
    bf16* wbufB = pos;                       // free after xca chan_pv (pw2 weights)

    // zero knsq + knsq_wa + S_xca + S_wa = 2,979,840 floats = 11640 * 256
    zero_kernel<<<11640, 256, 0, stream>>>(knsq);

    // pos embedding
    pos_kernel<<<4096, 128, 0, stream>>>(pos_w, pos_b, pos);

    // multi-scale depthwise conv chain -> P1 (xcat)
    dwconv_kernel<<<NBATCH * 96, 256, 0, stream>>>(x,   0, nullptr, 0,  convs_w,        convs_b,       P1, 0);
    dwconv_kernel<<<NBATCH * 96, 256, 0, stream>>>(x,  96, P1,      0,  convs_w + 864,  convs_b + 96,  P1, 96);
    dwconv_kernel<<<NBATCH * 96, 256, 0, stream>>>(x, 192, P1,     96,  convs_w + 1728, convs_b + 192, P1, 192);
    convert_last_kernel<<<6144, 256, 0, stream>>>(x, P1);

    // x3 = transpose(xcat) + pos -> P2
    x3_kernel<<<dim3(12, 128, NBATCH), dim3(32, 8), 0, stream>>>(P1, pos, P2);

    // XCA: LN -> kv (KT|V split, fused knormsq) -> MFMA attention -> proj = x4
    ln_kernel<<<NROWS, 128, 0, stream>>>(P2, ln_xca_w, ln_xca_b, P1, 0);
    wcvt_kernel<<<288, 256, 0, stream>>>(xca_kv_w, wbufA, 73728);        // 768x384
    mfma_gemm_kernel<<<dim3(512, 6), 256, 0, stream>>>(P1, wbufA, xca_kv_b, P3,
                                                       NROWS, 768, 384, 3, nullptr, nullptr, 12, knsq);
    chan_qk_mfma<<<512, 256, 0, stream>>>(x, nullptr, P3, S_xca, 4096, 8, 0);
    chan_softmax_kernel<<<64, 128, 0, stream>>>(S_xca, knsq, xca_temp, pos, 0);      // attn bf16 -> pos[0:589824]
    chan_pv_mfma<<<1024, 256, 0, stream>>>(pos, P3 + KVHALF, P1, 4096, 0);
    wcvt_kernel<<<144, 256, 0, stream>>>(xca_proj_w, wbufA, 36864);      // 384x384
    mfma_gemm_kernel<<<dim3(512, 3), 256, 0, stream>>>(P1, wbufA, xca_proj_b, P3,
                                                       NROWS, 384, 384, 2, P2, gamma_xca, 0, nullptr);  // x4 -> P3 lo

    // window attention
    unfold_cu_kernel<<<98304, 256, 0, stream>>>(x, P2);                                 // cu
    unfold_xu_kernel<<<98304, 256, 0, stream>>>(P3, conv_out_w, conv_out_b, P1);        // xu
    wcvt_kernel<<<288, 256, 0, stream>>>(wa_kv_w, wbufA, 73728);         // 768x384
    mfma_gemm_kernel<<<dim3(512, 6), 256, 0, stream>>>(P1, wbufA, wa_kv_b, P3,
                                                       NROWS, 768, 384, 3, nullptr, nullptr, 10, knsq_wa);
    chan_qk_mfma<<<512, 256, 0, stream>>>(nullptr, P2, P3, S_wa, 1024, 2, 1);
    chan_softmax_kernel<<<256, 128, 0, stream>>>(S_wa, knsq_wa, nullptr, P2, 1);        // attn bf16 -> P2 (cu dead)
    chan_pv_mfma<<<1024, 256, 0, stream>>>(P2, P3 + KVHALF, P1, 1024, 1);               // Xpre
    wcvt_kernel<<<144, 256, 0, stream>>>(wa_proj_w, wbufA, 36864);       // 384x384
    mfma_gemm_kernel<<<dim3(512, 3), 256, 0, stream>>>(P1, wbufA, wa_proj_b, P2,
                                                       NROWS, 384, 384, 0, nullptr, nullptr, 0, nullptr);  // Y

    // MLP: LN(fold remap) -> pw1(gelu) -> pw2, chunked 2x32768 rows
    // (P3 holds exactly 32768*1536 elems for the GELU intermediate)
    ln_kernel<<<NROWS, 128, 0, stream>>>(P2, ln_w, ln_b, P1, 1);
    wcvt_kernel<<<576, 256, 0, stream>>>(pw1_w, wbufA, 147456);          // 1536x384
    wcvt_kernel<<<576, 256, 0, stream>>>(pw2_w, wbufB, 147456);          // 384x1536
    for (int ch = 0; ch < 2; ++ch) {
        mfma_gemm_kernel<<<dim3(256, 12), 256, 0, stream>>>(P1 + (size_t)ch * 32768 * 384, wbufA, pw1_b,
                                                            P3, 32768, 1536, 384, 1, nullptr, nullptr, 0, nullptr);
        mfma_gemm_kernel<<<dim3(256, 3), 256, 0, stream>>>(P3, wbufB, pw2_b,
                                                           P2 + (size_t)ch * 32768 * 384, 32768, 384, 1536,
                                                           0, nullptr, nullptr, 0, nullptr);
    }

    // out = inp + gamma * final (transpose back to NCHW)
    out_kernel<<<dim3(12, 128, NBATCH), dim3(32, 8), 0, stream>>>(x, P2, gamma, out);
}

// Round 8
// 1242.172 us; speedup vs baseline: 1.1092x; 1.0170x over previous
//
#include <hip/hip_runtime.h>
#include <math.h>

// Problem constants
#define NBATCH 16
#define CDIM   384
#define NPIX   4096      // H*W = 64*64
#define HDCH   96        // channels per head
#define NROWS  65536     // NBATCH*NPIX
#define KVHALF 25165824  // 65536*384 = elems in KT (== elems in V)

typedef unsigned short bf16;
typedef __attribute__((ext_vector_type(8))) short short8;
typedef __attribute__((ext_vector_type(4))) float floatx4;

union S8U { short8 v; bf16 u[8]; };

__device__ __forceinline__ float b2f(bf16 u) {
    union { unsigned int i; float f; } c; c.i = ((unsigned int)u) << 16; return c.f;
}
__device__ __forceinline__ bf16 f2b(float f) {
    union { float f; unsigned int i; } c; c.f = f;
    unsigned int r = (c.i + 0x7FFFu + ((c.i >> 16) & 1u)) >> 16;
    return (bf16)r;
}

// async global->LDS, 16B per lane. LDS dest is wave-uniform base + lane*16.
__device__ __forceinline__ void gload16(const bf16* g, bf16* l) {
    __builtin_amdgcn_global_load_lds(
        (const __attribute__((address_space(1))) unsigned int*)g,
        (__attribute__((address_space(3))) unsigned int*)l, 16, 0, 0);
}

// unfold row permutation: r (unfold order) -> token row of x4 (b*4096 + y*64 + x)
__device__ __forceinline__ int unfold_src(int r) {
    int b2 = r >> 10, blk = r & 1023;
    int b = b2 >> 2, patch = b2 & 3;
    int y = ((blk >> 5) << 1) | (patch >> 1);
    int x = ((blk & 31) << 1) | (patch & 1);
    return b * NPIX + (y << 6) + x;
}

// ---------------------------------------------------------------------------
// 0) zero scratch accumulators
// ---------------------------------------------------------------------------
__global__ __launch_bounds__(256) void zero_kernel(float* __restrict__ p) {
    p[blockIdx.x * 256 + threadIdx.x] = 0.0f;
}

// 0b) convert fp32 weights -> bf16 (float4/ushort4 vectorized)
__global__ __launch_bounds__(256) void wcvt_kernel(const float* __restrict__ w,
                                                   bf16* __restrict__ o, int n4) {
    int i = blockIdx.x * 256 + threadIdx.x;
    if (i < n4) {
        float4 v = ((const float4*)w)[i];
        ushort4 u;
        u.x = f2b(v.x); u.y = f2b(v.y); u.z = f2b(v.z); u.w = f2b(v.w);
        ((ushort4*)o)[i] = u;
    }
}

// 0c) convert + per-k scale: o[col][k] = w[col][k] * cw[k]  (K=384, row-major)
__global__ __launch_bounds__(256) void wcvt_scale_kernel(const float* __restrict__ w,
                                                         const float* __restrict__ cw,
                                                         bf16* __restrict__ o, int n4) {
    int i = blockIdx.x * 256 + threadIdx.x;
    if (i < n4) {
        float4 v = ((const float4*)w)[i];
        float4 s = ((const float4*)cw)[i % 96];   // k = (i%96)*4 ..
        ushort4 u;
        u.x = f2b(v.x * s.x); u.y = f2b(v.y * s.y);
        u.z = f2b(v.z * s.z); u.w = f2b(v.w * s.w);
        ((ushort4*)o)[i] = u;
    }
}

// 0d) bias fold: o[col] = b[col] + sum_k w[col][k]*cb[k]   (768 cols, K=384)
__global__ __launch_bounds__(256) void biasfold_kernel(const float* __restrict__ w,
                                                       const float* __restrict__ b,
                                                       const float* __restrict__ cb,
                                                       float* __restrict__ o) {
    int col = blockIdx.x * 256 + threadIdx.x;
    if (col < 768) {
        float s = b[col];
        const float* wr = w + col * 384;
        #pragma unroll 8
        for (int k = 0; k < 384; ++k) s += wr[k] * cb[k];
        o[col] = s;
    }
}

// ---------------------------------------------------------------------------
// 1) Fourier positional embedding: pos[n, c] (bf16 out)
// ---------------------------------------------------------------------------
__global__ __launch_bounds__(128) void pos_kernel(const float* __restrict__ pos_w,
                                                  const float* __restrict__ pos_b,
                                                  bf16* __restrict__ pos) {
    __shared__ float feat[64];
    int n = blockIdx.x;
    int yi = n >> 6, xi = n & 63;
    int tid = threadIdx.x;
    if (tid < 64) {
        int j = tid & 31;
        int isx = tid >= 32;
        float base = (float)((isx ? xi : yi) + 1);
        float val = base / (64.0f + 1e-6f) * 6.283185307179586f;
        float e = (float)(2 * (j >> 1)) / 32.0f;
        float dt = powf(10000.0f, e);
        float a = val / dt;
        feat[isx * 32 + j] = (j & 1) ? cosf(a) : sinf(a);
    }
    __syncthreads();
    for (int c = tid; c < CDIM; c += 128) {
        float s = pos_b[c];
        const float* wr = pos_w + c * 64;
        #pragma unroll 16
        for (int j = 0; j < 64; ++j) s += feat[j] * wr[j];
        pos[n * CDIM + c] = f2b(s);
    }
}

// ---------------------------------------------------------------------------
// 2) Depthwise 3x3 conv (pad 1). xin fp32 chunk (+ prev bf16 chunk), out bf16.
// ---------------------------------------------------------------------------
__global__ __launch_bounds__(256) void dwconv_kernel(const float* __restrict__ xin, int in_ch0,
                                                     const bf16* __restrict__ prev, int prev_ch0,
                                                     const float* __restrict__ w,
                                                     const float* __restrict__ bias,
                                                     bf16* __restrict__ out, int out_ch0) {
    __shared__ float tile[66][66];
    int b = blockIdx.x / 96, c = blockIdx.x % 96;
    const float* ip = xin + (b * CDIM + in_ch0 + c) * NPIX;
    const bf16* pp = prev ? prev + (b * CDIM + prev_ch0 + c) * NPIX : nullptr;
    int tid = threadIdx.x;
    for (int i = tid; i < 66 * 66; i += 256) {
        int yy = i / 66 - 1, xx = i % 66 - 1;
        float v = 0.0f;
        if (yy >= 0 && yy < 64 && xx >= 0 && xx < 64) {
            v = ip[yy * 64 + xx];
            if (pp) v += b2f(pp[yy * 64 + xx]);
        }
        tile[i / 66][i % 66] = v;
    }
    __syncthreads();
    float wc[9];
    #pragma unroll
    for (int j = 0; j < 9; ++j) wc[j] = w[c * 9 + j];
    float b0 = bias[c];
    bf16* op = out + (b * CDIM + out_ch0 + c) * NPIX;
    for (int p = tid; p < NPIX; p += 256) {
        int y = p >> 6, x = p & 63;
        float a = b0;
        #pragma unroll
        for (int dy = 0; dy < 3; ++dy)
            #pragma unroll
            for (int dx = 0; dx < 3; ++dx)
                a += tile[y + dy][x + dx] * wc[dy * 3 + dx];
        op[p] = f2b(a);
    }
}

// convert channels [288:384) of x (fp32) into xcat (bf16)
__global__ __launch_bounds__(256) void convert_last_kernel(const float* __restrict__ x,
                                                           bf16* __restrict__ xcat) {
    int idx = blockIdx.x * 256 + threadIdx.x;   // 16*96*4096/4 = 1,572,864 threads
    int b = idx / (96 * 1024);
    int rem = idx % (96 * 1024);
    const float4* src = (const float4*)(x + (b * CDIM + 288) * NPIX);
    float4 v = src[rem];
    ushort4 o;
    o.x = f2b(v.x); o.y = f2b(v.y); o.z = f2b(v.z); o.w = f2b(v.w);
    ((ushort4*)(xcat + (b * CDIM + 288) * NPIX))[rem] = o;
}

// ---------------------------------------------------------------------------
// 3) x3[b,n,c] = xcat[b,c,n] + pos[n,c]   (LDS 32x32 transpose, bf16 io)
// ---------------------------------------------------------------------------
__global__ void x3_kernel(const bf16* __restrict__ xcat, const bf16* __restrict__ pos,
                          bf16* __restrict__ x3) {
    __shared__ float t[32][33];
    int c0 = blockIdx.x * 32, n0 = blockIdx.y * 32, b = blockIdx.z;
    int tx = threadIdx.x, ty = threadIdx.y;
    #pragma unroll
    for (int k = 0; k < 4; ++k) {
        int cl = ty + k * 8;
        t[cl][tx] = b2f(xcat[(b * CDIM + c0 + cl) * NPIX + n0 + tx]);
    }
    __syncthreads();
    #pragma unroll
    for (int k = 0; k < 4; ++k) {
        int nl = ty + k * 8;
        x3[(b * NPIX + n0 + nl) * CDIM + c0 + tx] =
            f2b(t[tx][nl] + b2f(pos[(n0 + nl) * CDIM + c0 + tx]));
    }
}

// ---------------------------------------------------------------------------
// 4) Row LayerNorm over C=384, bf16 io. map=1: fold-remap source row.
// ---------------------------------------------------------------------------
__global__ __launch_bounds__(128) void ln_kernel(const bf16* __restrict__ in,
                                                 const float* __restrict__ w,
                                                 const float* __restrict__ b,
                                                 bf16* __restrict__ out, int map) {
    int r = blockIdx.x;
    int src = r;
    if (map == 1) {
        int bb = r >> 12;
        int p = r & 4095;
        int y = p >> 6, x = p & 63;
        int patch = ((y & 1) << 1) | (x & 1);
        int blk = ((y >> 1) << 5) | (x >> 1);
        src = ((bb << 2) + patch) * 1024 + blk;
    }
    const bf16* row = in + src * CDIM;
    int tid = threadIdx.x;
    float v[3];
    float s1 = 0.0f, s2 = 0.0f;
    #pragma unroll
    for (int i = 0; i < 3; ++i) {
        v[i] = b2f(row[tid + i * 128]);
        s1 += v[i];
        s2 += v[i] * v[i];
    }
    __shared__ float r1[128], r2[128];
    r1[tid] = s1; r2[tid] = s2;
    __syncthreads();
    for (int off = 64; off > 0; off >>= 1) {
        if (tid < off) { r1[tid] += r1[tid + off]; r2[tid] += r2[tid + off]; }
        __syncthreads();
    }
    float mean = r1[0] * (1.0f / 384.0f);
    float var = fmaxf(r2[0] * (1.0f / 384.0f) - mean * mean, 0.0f);
    float rstd = rsqrtf(var + 1e-6f);
    #pragma unroll
    for (int i = 0; i < 3; ++i) {
        int c = tid + i * 128;
        out[r * CDIM + c] = f2b((v[i] - mean) * rstd * w[c] + b[c]);
    }
}

// ---------------------------------------------------------------------------
// 5) MFMA GEMM: C[M,Nout] = epi(A[M,K](bf16) @ W[Nout,K]^T(bf16) + bias)
//    128x128 tile, BK=32, 4 waves, 16x16x32 bf16 MFMA.
//    3-buffer depth-2 software pipeline (measured best; deeper = occupancy loss):
//      iter t: STAGE(buf[(t+2)%3]) ; compute buf[t%3] ; vmcnt(4) ; s_barrier
//    XCD-chunked swizzle (T1) + panel-major decompose: A fetched from HBM once.
//    Staging: global_load_lds width-16, linear LDS with involution swizzle.
//    aremap=1: A-row index passes through the unfold permutation (fuses the
//    unfold gather into staging; per-thread, loop-invariant).
//    mode 0: plain   mode 1: fast GELU   mode 2: res(bf16) + scalevec[c]*(.)
//    NOTE: res/C are NOT restrict-qualified — mode 2 may be called with
//    res == C (in-place residual add); each address is read-then-written by
//    exactly one thread.
//    mode 3: kv-split — cols<384 write transposed KT + fused knormsq atomics;
//            cols>=384 write V at C+KVHALF, [row][col-384]
// ---------------------------------------------------------------------------
__global__ __launch_bounds__(256) void mfma_gemm_kernel(const bf16* __restrict__ A,
                                                        const bf16* __restrict__ W,
                                                        const float* __restrict__ bias,
                                                        bf16* C,
                                                        int M, int Nout, int K, int mode,
                                                        const bf16* res,
                                                        const float* __restrict__ scalevec,
                                                        int nlog2,
                                                        float* __restrict__ knsq_out,
                                                        int aremap) {
    __shared__ bf16 As[3][128][32];   // 24 KB
    __shared__ bf16 Bs[3][128][32];   // 24 KB
    // --- XCD-chunked swizzle + panel-major decomposition ---
    int nx = gridDim.x, ny = gridDim.y;
    int d = blockIdx.x + nx * blockIdx.y;     // flat dispatch id (x fastest)
    int nwg = nx * ny;
    int xt, yt;
    if ((nwg & 7) == 0) {
        int cpx = nwg >> 3;
        int wg = (d & 7) * cpx + (d >> 3);    // contiguous range per XCD
        xt = wg / ny;                         // A-panel index (owned by one XCD)
        yt = wg % ny;
    } else {
        xt = blockIdx.x; yt = blockIdx.y;
    }
    int m0 = xt * 128;
    int n0 = yt * 128;
    int tid = threadIdx.x;
    int wave = tid >> 6, lane = tid & 63;
    int wm = (wave & 1) * 64;
    int wn = (wave >> 1) * 64;
    int quad = lane >> 4;
    int lrow = lane & 15;

    // --- staging address decomposition (per-thread, loop-invariant) ---
    int p0b = wave * 1024 + lane * 16;
    int o0 = p0b ^ (((p0b >> 7) & 3) << 4);
    int r0 = o0 >> 6;
    int ch0 = (o0 >> 4) & 3;

    int ar0 = m0 + r0, ar1 = m0 + r0 + 64;
    if (aremap) { ar0 = unfold_src(ar0); ar1 = unfold_src(ar1); }
    const bf16* aSrc0 = A + (size_t)ar0 * K + ch0 * 8;
    const bf16* aSrc1 = A + (size_t)ar1 * K + ch0 * 8;
    const bf16* bSrc0 = W + (size_t)(n0 + r0) * K + ch0 * 8;
    const bf16* bSrc1 = W + (size_t)(n0 + r0 + 64) * K + ch0 * 8;
    bf16* lA0 = &As[0][0][0] + wave * 512;          // wave-uniform LDS bases (buffer 0)
    bf16* lA1 = &As[0][0][0] + 2048 + wave * 512;
    bf16* lB0 = &Bs[0][0][0] + wave * 512;
    bf16* lB1 = &Bs[0][0][0] + 2048 + wave * 512;

    // swizzled read column (elems)
    int rcol = (quad ^ ((lrow >> 1) & 3)) * 8;
    int NT = K >> 5;

#define STAGE(bi_, t_) do { int _off = (bi_) * 4096; int _kk = (t_) * 32; \
        gload16(aSrc0 + _kk, lA0 + _off); \
        gload16(aSrc1 + _kk, lA1 + _off); \
        gload16(bSrc0 + _kk, lB0 + _off); \
        gload16(bSrc1 + _kk, lB1 + _off); } while (0)

    floatx4 acc[4][4] = {};

    // prologue: two tiles in flight, wait for tile 0 only
    STAGE(0, 0);
    STAGE(1, 1);
    asm volatile("s_waitcnt vmcnt(4)" ::: "memory");
    __builtin_amdgcn_s_barrier();
    __builtin_amdgcn_sched_barrier(0);

    for (int t = 0; t < NT; ++t) {
        int bi = t % 3;
        if (t + 2 < NT) STAGE((t + 2) % 3, t + 2);   // safe: readers of this buf passed barrier(t-1)
        short8 af[4], bfr[4];
        #pragma unroll
        for (int i = 0; i < 4; ++i)
            af[i] = *(const short8*)(&As[bi][wm + i * 16 + lrow][rcol]);
        #pragma unroll
        for (int j = 0; j < 4; ++j)
            bfr[j] = *(const short8*)(&Bs[bi][wn + j * 16 + lrow][rcol]);
        #pragma unroll
        for (int i = 0; i < 4; ++i)
            #pragma unroll
            for (int j = 0; j < 4; ++j)
                acc[i][j] = __builtin_amdgcn_mfma_f32_16x16x32_bf16(af[i], bfr[j], acc[i][j], 0, 0, 0);
        if (t + 1 < NT) {
            if (t + 2 < NT) asm volatile("s_waitcnt vmcnt(4)" ::: "memory");  // t+1 landed, t+2 in flight
            else            asm volatile("s_waitcnt vmcnt(0)" ::: "memory");  // last prefetch landed
            __builtin_amdgcn_s_barrier();
            __builtin_amdgcn_sched_barrier(0);
        }
    }
#undef STAGE

    if (mode == 3) {
        int nmask = (1 << nlog2) - 1;
        #pragma unroll
        for (int j = 0; j < 4; ++j) {
            int col = n0 + wn + j * 16 + lrow;
            float bv = bias[col];
            if (col < 384) {
                float ss = 0.0f;
                #pragma unroll
                for (int i = 0; i < 4; ++i) {
                    int rowb = m0 + wm + i * 16 + quad * 4;
                    int bb = rowb >> nlog2, tok = rowb & nmask;
                    float v0 = acc[i][j][0] + bv;
                    float v1 = acc[i][j][1] + bv;
                    float v2 = acc[i][j][2] + bv;
                    float v3 = acc[i][j][3] + bv;
                    ss += v0 * v0 + v1 * v1 + v2 * v2 + v3 * v3;
                    ushort4 o;
                    o.x = f2b(v0); o.y = f2b(v1); o.z = f2b(v2); o.w = f2b(v3);
                    *(ushort4*)(C + ((((size_t)bb * 384 + col) << nlog2) | (size_t)tok)) = o;
                }
                int bb0 = (m0 + wm) >> nlog2;
                atomicAdd(&knsq_out[bb0 * CDIM + col], ss);
            } else {
                #pragma unroll
                for (int i = 0; i < 4; ++i) {
                    int rowb = m0 + wm + i * 16 + quad * 4;
                    bf16* vp = C + KVHALF + (size_t)rowb * 384 + (col - 384);
                    #pragma unroll
                    for (int r = 0; r < 4; ++r)
                        vp[(size_t)r * 384] = f2b(acc[i][j][r] + bv);
                }
            }
        }
        return;
    }

    // epilogue: D row = quad*4+reg (within 16-tile), col = lrow
    #pragma unroll
    for (int i = 0; i < 4; ++i) {
        int rowb = m0 + wm + i * 16 + quad * 4;
        #pragma unroll
        for (int j = 0; j < 4; ++j) {
            int col = n0 + wn + j * 16 + lrow;
            float bv = bias[col];
            #pragma unroll
            for (int r = 0; r < 4; ++r) {
                int row = rowb + r;
                float v = acc[i][j][r] + bv;
                if (mode == 1) {
                    // fast GELU: v*sigmoid(1.5957691*(v+0.044715 v^3))
                    float t = __expf(-1.5957691216057308f * (v + 0.044715f * v * v * v));
                    v = v / (1.0f + t);
                } else if (mode == 2) {
                    v = b2f(res[(size_t)row * Nout + col]) + scalevec[col] * v;
                }
                C[(size_t)row * Nout + col] = f2b(v);
            }
        }
    }
}

// ---------------------------------------------------------------------------
// 7a) S accumulate via MFMA: S[pair,c,d] += sum_{n in chunk} Q[c,n]*K[d,n]
// ---------------------------------------------------------------------------
__global__ __launch_bounds__(256) void chan_qk_mfma(const float* __restrict__ qf,
                                                    const bf16* __restrict__ qb,
                                                    const bf16* __restrict__ KT,
                                                    float* __restrict__ Sg,
                                                    int n_len, int nchunks, int mode) {
    int pair = blockIdx.x / nchunks, ck = blockIdx.x % nchunks;
    int bi = pair >> 2, h = pair & 3;
    int koff = h * HDCH;
    int chunk = n_len / nchunks;
    int nbeg = ck * chunk;
    int tid = threadIdx.x;
    int wave = tid >> 6, lane = tid & 63;
    int lr = lane & 15, q = lane >> 4;
    int c0 = (wave & 1) * 48;
    int d0 = (wave >> 1) * 48;
    floatx4 acc[3][3] = {};
    const size_t qbase = (size_t)(bi * CDIM + koff) * n_len;
    const bf16* kbase = KT + (size_t)(bi * CDIM + koff) * n_len;
    for (int nn = 0; nn < chunk; nn += 32) {
        int n0 = nbeg + nn + q * 8;
        short8 af[3], bfr[3];
        if (mode == 0) {
            #pragma unroll
            for (int i = 0; i < 3; ++i) {
                const float* qp = qf + qbase + (size_t)(c0 + i * 16 + lr) * n_len + n0;
                float4 f0 = *(const float4*)qp;
                float4 f1 = *(const float4*)(qp + 4);
                S8U t;
                t.u[0] = f2b(f0.x); t.u[1] = f2b(f0.y); t.u[2] = f2b(f0.z); t.u[3] = f2b(f0.w);
                t.u[4] = f2b(f1.x); t.u[5] = f2b(f1.y); t.u[6] = f2b(f1.z); t.u[7] = f2b(f1.w);
                af[i] = t.v;
            }
        } else {
            #pragma unroll
            for (int i = 0; i < 3; ++i)
                af[i] = *(const short8*)(qb + qbase + (size_t)(c0 + i * 16 + lr) * n_len + n0);
        }
        #pragma unroll
        for (int j = 0; j < 3; ++j)
            bfr[j] = *(const short8*)(kbase + (size_t)(d0 + j * 16 + lr) * n_len + n0);
        #pragma unroll
        for (int i = 0; i < 3; ++i)
            #pragma unroll
            for (int j = 0; j < 3; ++j)
                acc[i][j] = __builtin_amdgcn_mfma_f32_16x16x32_bf16(af[i], bfr[j], acc[i][j], 0, 0, 0);
    }
    float* Sp = Sg + (size_t)pair * 9216;
    #pragma unroll
    for (int i = 0; i < 3; ++i) {
        int rowb = c0 + i * 16 + q * 4;
        #pragma unroll
        for (int j = 0; j < 3; ++j) {
            int col = d0 + j * 16 + lr;
            #pragma unroll
            for (int r = 0; r < 4; ++r)
                atomicAdd(&Sp[(rowb + r) * 96 + col], acc[i][j][r]);
        }
    }
}

// ---------------------------------------------------------------------------
// 7b) softmax rows of S. Applies per-d l2norm scale (knrm) first.
//     mode 0: softmax(S*knrm*temp[h]); mode 1: double softmax.
//     Writes attn as bf16 to Sb (consumed by MFMA PV).
// ---------------------------------------------------------------------------
__global__ __launch_bounds__(128) void chan_softmax_kernel(const float* __restrict__ Sg,
                                                           const float* __restrict__ knsq,
                                                           const float* __restrict__ temp,
                                                           bf16* __restrict__ Sb,
                                                           int mode) {
    __shared__ float knrm[96];
    int pair = blockIdx.x;
    int bi = pair >> 2, h = pair & 3;
    int tid = threadIdx.x;
    if (tid < 96)
        knrm[tid] = 1.0f / fmaxf(sqrtf(knsq[bi * CDIM + h * HDCH + tid]), 1e-12f);
    __syncthreads();
    if (tid >= 96) return;
    const float* Sr = Sg + (size_t)pair * 9216 + tid * 96;
    bf16* Ob = Sb + (size_t)pair * 9216 + tid * 96;
    if (mode == 0) {
        float tv = temp[h];
        float m = -1e30f;
        for (int d = 0; d < 96; ++d) m = fmaxf(m, Sr[d] * knrm[d] * tv);
        float s = 0.0f;
        for (int d = 0; d < 96; ++d) s += expf(Sr[d] * knrm[d] * tv - m);
        float inv = 1.0f / s;
        for (int d = 0; d < 96; ++d) Ob[d] = f2b(expf(Sr[d] * knrm[d] * tv - m) * inv);
    } else {
        const float RSQ = 0.10206207261596575f;  // 1/sqrt(96)
        float m1 = -1e30f;
        for (int d = 0; d < 96; ++d) m1 = fmaxf(m1, Sr[d] * knrm[d]);
        float s1 = 0.0f;
        for (int d = 0; d < 96; ++d) s1 += expf(Sr[d] * knrm[d] - m1);
        float inv1 = 1.0f / s1;
        float m2 = -1e30f;
        for (int d = 0; d < 96; ++d) {
            float l = Sr[d] * knrm[d];
            float a = 0.5f * l * RSQ + 0.5f * expf(l - m1) * inv1;
            m2 = fmaxf(m2, a);
        }
        float s2 = 0.0f;
        for (int d = 0; d < 96; ++d) {
            float l = Sr[d] * knrm[d];
            float a = 0.5f * l * RSQ + 0.5f * expf(l - m1) * inv1;
            s2 += expf(a - m2);
        }
        float inv2 = 1.0f / s2;
        for (int d = 0; d < 96; ++d) {
            float l = Sr[d] * knrm[d];
            float a = 0.5f * l * RSQ + 0.5f * expf(l - m1) * inv1;
            Ob[d] = f2b(expf(a - m2) * inv2);
        }
    }
}

// ---------------------------------------------------------------------------
// 7c) PV via MFMA: out[c,n] = sum_d attn[c,d]*V[d,n].
// ---------------------------------------------------------------------------
#define PVTN 256
__global__ __launch_bounds__(256) void chan_pv_mfma(const bf16* __restrict__ Sb,
                                                    const bf16* __restrict__ V,
                                                    bf16* __restrict__ out,
                                                    int n_len, int mode) {
    int nch = n_len / PVTN;
    int pair = blockIdx.x / nch, ck = blockIdx.x % nch;
    int bi = pair >> 2, h = pair & 3;
    int koff = h * HDCH;
    int tid = threadIdx.x;
    int wave = tid >> 6, lane = tid & 63;
    int lr = lane & 15, q = lane >> 4;
    const bf16* Ab = Sb + (size_t)pair * 9216;
    short8 af[6][3];
    #pragma unroll
    for (int i = 0; i < 6; ++i)
        #pragma unroll
        for (int kt = 0; kt < 3; ++kt)
            af[i][kt] = *(const short8*)(Ab + (i * 16 + lr) * 96 + kt * 32 + q * 8);
    const bf16* vb = V + (size_t)bi * n_len * 384 + koff;
    int nbase = ck * PVTN + wave * 16;
    #pragma unroll
    for (int s = 0; s < 4; ++s) {
        int n = nbase + s * 64 + lr;
        short8 bfr[3];
        #pragma unroll
        for (int kt = 0; kt < 3; ++kt)
            bfr[kt] = *(const short8*)(vb + (size_t)n * 384 + kt * 32 + q * 8);
        floatx4 acc[6] = {};
        #pragma unroll
        for (int kt = 0; kt < 3; ++kt)
            #pragma unroll
            for (int i = 0; i < 6; ++i)
                acc[i] = __builtin_amdgcn_mfma_f32_16x16x32_bf16(af[i][kt], bfr[kt], acc[i], 0, 0, 0);
        if (mode == 0) {
            bf16* op = out + (size_t)(bi * n_len + n) * CDIM + koff;
            #pragma unroll
            for (int i = 0; i < 6; ++i) {
                ushort4 o;
                o.x = f2b(acc[i][0]); o.y = f2b(acc[i][1]);
                o.z = f2b(acc[i][2]); o.w = f2b(acc[i][3]);
                *(ushort4*)(op + i * 16 + q * 4) = o;
            }
        } else {
            #pragma unroll
            for (int i = 0; i < 6; ++i) {
                int cb = i * 16 + q * 4;
                #pragma unroll
                for (int r = 0; r < 4; ++r)
                    out[(size_t)((h * 64 + bi) * HDCH + cb + r) * n_len + n] = f2b(acc[i][r]);
            }
        }
    }
}

// ---------------------------------------------------------------------------
// 8) Unfold gather (cu only; xu is fused into the wa kv GEMM)
// ---------------------------------------------------------------------------
__global__ __launch_bounds__(256) void unfold_cu_kernel(const float* __restrict__ xin,
                                                        bf16* __restrict__ cu) {
    int idx = blockIdx.x * 256 + threadIdx.x;    // 64*384*1024 total
    int b2 = idx / (CDIM * 1024);
    int rem = idx % (CDIM * 1024);
    int ch = rem >> 10, blk = rem & 1023;
    int b = b2 >> 2, patch = b2 & 3;
    int y = ((blk >> 5) << 1) | (patch >> 1);
    int x = ((blk & 31) << 1) | (patch & 1);
    cu[idx] = f2b(xin[(size_t)(b * CDIM + ch) * NPIX + (y << 6) + x]);
}

// ---------------------------------------------------------------------------
// 9) out[b,c,p] = inp[b,c,p] + gamma[c] * final[(b*4096+p), c]  (fp32 out)
// ---------------------------------------------------------------------------
__global__ void out_kernel(const float* __restrict__ xin, const bf16* __restrict__ fin,
                           const float* __restrict__ gamma, float* __restrict__ outp) {
    __shared__ float t[32][33];
    int c0 = blockIdx.x * 32, p0 = blockIdx.y * 32, b = blockIdx.z;
    int tx = threadIdx.x, ty = threadIdx.y;
    #pragma unroll
    for (int k = 0; k < 4; ++k) {
        int pl = ty + k * 8;
        t[pl][tx] = b2f(fin[(size_t)(b * NPIX + p0 + pl) * CDIM + c0 + tx]);
    }
    __syncthreads();
    #pragma unroll
    for (int k = 0; k < 4; ++k) {
        int cl = ty + k * 8;
        size_t addr = (size_t)(b * CDIM + c0 + cl) * NPIX + p0 + tx;
        outp[addr] = xin[addr] + gamma[c0 + cl] * t[tx][cl];
    }
}

// ---------------------------------------------------------------------------
extern "C" void kernel_launch(void* const* d_in, const int* in_sizes, int n_in,
                              void* d_out, int out_size, void* d_ws, size_t ws_size,
                              hipStream_t stream) {
    (void)in_sizes; (void)n_in; (void)out_size; (void)ws_size;
    const float* x         = (const float*)d_in[0];
    const float* convs_w   = (const float*)d_in[1];
    const float* convs_b   = (const float*)d_in[2];
    const float* pos_w     = (const float*)d_in[3];
    const float* pos_b     = (const float*)d_in[4];
    const float* ln_xca_w  = (const float*)d_in[5];
    const float* ln_xca_b  = (const float*)d_in[6];
    const float* gamma_xca = (const float*)d_in[7];
    const float* xca_temp  = (const float*)d_in[8];
    const float* xca_kv_w  = (const float*)d_in[9];
    const float* xca_kv_b  = (const float*)d_in[10];
    const float* xca_proj_w= (const float*)d_in[11];
    const float* xca_proj_b= (const float*)d_in[12];
    const float* conv_out_w= (const float*)d_in[13];
    const float* conv_out_b= (const float*)d_in[14];
    const float* wa_kv_w   = (const float*)d_in[15];
    const float* wa_kv_b   = (const float*)d_in[16];
    const float* wa_proj_w = (const float*)d_in[17];
    const float* wa_proj_b = (const float*)d_in[18];
    const float* ln_w      = (const float*)d_in[19];
    const float* ln_b      = (const float*)d_in[20];
    const float* pw1_w     = (const float*)d_in[21];
    const float* pw1_b     = (const float*)d_in[22];
    const float* pw2_w     = (const float*)d_in[23];
    const float* pw2_b     = (const float*)d_in[24];
    const float* gamma     = (const float*)d_in[25];
    float* out = (float*)d_out;

    // Workspace: bf16 pools + fp32 accumulators. Total ~216 MiB (unchanged).
    bf16* pos = (bf16*)d_ws;                 // 1,572,864 elems
    bf16* P1  = pos + 1572864;               // 25,165,824 elems
    bf16* P2  = P1 + 25165824;               // 25,165,824 elems
    bf16* P3  = P2 + 25165824;               // 50,331,648 elems (KT | V during attn)
    float* knsq    = (float*)(P3 + 50331648);// 6,144  (xca)
    float* knsq_wa = knsq + 6144;            // 24,576 (wa)
    float* S_xca   = knsq_wa + 24576;        // 64*9216   = 589,824
    float* S_wa    = S_xca + 589824;         // 256*9216  = 2,359,296

    // bf16 weight staging, inside the pos pool:
    bf16* wbufA = pos + 589824;              // capacity 983,040 elems
    bf16* wbufB = pos;                       // free after xca chan_pv (pw2 weights)
    // folded wa_kv bias (768 floats): reuse S_xca head (dead after xca softmax)
    float* bias_wa = S_xca;

    // zero knsq + knsq_wa + S_xca + S_wa = 2,979,840 floats = 11640 * 256
    zero_kernel<<<11640, 256, 0, stream>>>(knsq);

    // pos embedding
    pos_kernel<<<4096, 128, 0, stream>>>(pos_w, pos_b, pos);

    // multi-scale depthwise conv chain -> P1 (xcat)
    dwconv_kernel<<<NBATCH * 96, 256, 0, stream>>>(x,   0, nullptr, 0,  convs_w,        convs_b,       P1, 0);
    dwconv_kernel<<<NBATCH * 96, 256, 0, stream>>>(x,  96, P1,      0,  convs_w + 864,  convs_b + 96,  P1, 96);
    dwconv_kernel<<<NBATCH * 96, 256, 0, stream>>>(x, 192, P1,     96,  convs_w + 1728, convs_b + 192, P1, 192);
    convert_last_kernel<<<6144, 256, 0, stream>>>(x, P1);

    // x3 = transpose(xcat) + pos -> P2
    x3_kernel<<<dim3(12, 128, NBATCH), dim3(32, 8), 0, stream>>>(P1, pos, P2);

    // XCA: LN -> kv (KT|V split, fused knormsq) -> MFMA attention -> proj = x4
    ln_kernel<<<NROWS, 128, 0, stream>>>(P2, ln_xca_w, ln_xca_b, P1, 0);
    wcvt_kernel<<<288, 256, 0, stream>>>(xca_kv_w, wbufA, 73728);        // 768x384
    mfma_gemm_kernel<<<dim3(512, 6), 256, 0, stream>>>(P1, wbufA, xca_kv_b, P3,
                                                       NROWS, 768, 384, 3, nullptr, nullptr, 12, knsq, 0);
    chan_qk_mfma<<<512, 256, 0, stream>>>(x, nullptr, P3, S_xca, 4096, 8, 0);
    chan_softmax_kernel<<<64, 128, 0, stream>>>(S_xca, knsq, xca_temp, pos, 0);      // attn bf16 -> pos[0:589824]
    chan_pv_mfma<<<1024, 256, 0, stream>>>(pos, P3 + KVHALF, P1, 4096, 0);
    wcvt_kernel<<<144, 256, 0, stream>>>(xca_proj_w, wbufA, 36864);      // 384x384
    // x4 written IN-PLACE into P2 (res == C): each address read-then-written by
    // exactly one thread; res/C are unqualified in the kernel signature.
    mfma_gemm_kernel<<<dim3(512, 3), 256, 0, stream>>>(P1, wbufA, xca_proj_b, P2,
                                                       NROWS, 384, 384, 2, P2, gamma_xca, 0, nullptr, 0);

    // window attention — conv_out affine folded into kv weights/bias;
    // unfold gather folded into the GEMM A-row remap (aremap=1).
    biasfold_kernel<<<3, 256, 0, stream>>>(wa_kv_w, wa_kv_b, conv_out_b, bias_wa);
    wcvt_scale_kernel<<<288, 256, 0, stream>>>(wa_kv_w, conv_out_w, wbufA, 73728);
    mfma_gemm_kernel<<<dim3(512, 6), 256, 0, stream>>>(P2, wbufA, bias_wa, P3,
                                                       NROWS, 768, 384, 3, nullptr, nullptr, 10, knsq_wa, 1);
    unfold_cu_kernel<<<98304, 256, 0, stream>>>(x, P1);                                 // cu -> P1
    chan_qk_mfma<<<512, 256, 0, stream>>>(nullptr, P1, P3, S_wa, 1024, 2, 1);
    chan_softmax_kernel<<<256, 128, 0, stream>>>(S_wa, knsq_wa, nullptr, P2, 1);        // attn bf16 -> P2 (x4 dead)
    chan_pv_mfma<<<1024, 256, 0, stream>>>(P2, P3 + KVHALF, P1, 1024, 1);               // Xpre -> P1 (cu dead)
    wcvt_kernel<<<144, 256, 0, stream>>>(wa_proj_w, wbufA, 36864);       // 384x384
    mfma_gemm_kernel<<<dim3(512, 3), 256, 0, stream>>>(P1, wbufA, wa_proj_b, P2,
                                                       NROWS, 384, 384, 0, nullptr, nullptr, 0, nullptr, 0);  // Y

    // MLP: LN(fold remap) -> pw1(gelu) -> pw2, chunked 2x32768 rows
    // (P3 holds exactly 32768*1536 elems for the GELU intermediate)
    ln_kernel<<<NROWS, 128, 0, stream>>>(P2, ln_w, ln_b, P1, 1);
    wcvt_kernel<<<576, 256, 0, stream>>>(pw1_w, wbufA, 147456);          // 1536x384
    wcvt_kernel<<<576, 256, 0, stream>>>(pw2_w, wbufB, 147456);          // 384x1536
    for (int ch = 0; ch < 2; ++ch) {
        mfma_gemm_kernel<<<dim3(256, 12), 256, 0, stream>>>(P1 + (size_t)ch * 32768 * 384, wbufA, pw1_b,
                                                            P3, 32768, 1536, 384, 1, nullptr, nullptr, 0, nullptr, 0);
        mfma_gemm_kernel<<<dim3(256, 3), 256, 0, stream>>>(P3, wbufB, pw2_b,
                                                           P2 + (size_t)ch * 32768 * 384, 32768, 384, 1536,
                                                           0, nullptr, nullptr, 0, nullptr, 0);
    }

    // out = inp + gamma * final (transpose back to NCHW)
    out_kernel<<<dim3(12, 128, NBATCH), dim3(32, 8), 0, stream>>>(x, P2, gamma, out);
}